// Round 19
// baseline (282.475 us; speedup 1.0000x reference)
//
#include <hip/hip_runtime.h>
#include <hip/hip_cooperative_groups.h>

namespace cg = cooperative_groups;

#define NF 64      // hidden width (both layers)
#define NBLK 256   // chunks for the bucket sort == cooperative grid size (1 block/CU)
#define SH 8       // bucket = dst >> SH  (256 nodes per bucket)
#define BMSK 255
#define MAXNB 2048 // LDS histogram capacity (NB = ceil(n/256) <= 2048)

typedef unsigned short ushort_t;
typedef __attribute__((ext_vector_type(8))) short short8;   // 8 bf16 = 4 VGPR (MFMA A/B frag)
typedef __attribute__((ext_vector_type(4))) float f32x4;    // MFMA C/D frag

__device__ inline ushort_t f2bf(float f) {               // RNE f32 -> bf16
    unsigned u = __float_as_uint(f);
    return (ushort_t)((u + 0x7fffu + ((u >> 16) & 1u)) >> 16);
}
__device__ inline float bfhi(unsigned x) { return __uint_as_float(x & 0xffff0000u); }
__device__ inline float bflo(unsigned x) { return __uint_as_float(x << 16); }

#define PACK8(b, ua, ub) \
    b[0] = (short)f2bf(ua.x); b[1] = (short)f2bf(ua.y); \
    b[2] = (short)f2bf(ua.z); b[3] = (short)f2bf(ua.w); \
    b[4] = (short)f2bf(ub.x); b[5] = (short)f2bf(ub.y); \
    b[6] = (short)f2bf(ub.z); b[7] = (short)f2bf(ub.w);

__device__ inline int wave_incl_scan(int x, int lane) {
#pragma unroll
    for (int o = 1; o < 64; o <<= 1) { int y = __shfl_up(x, o, 64); if (lane >= o) x += y; }
    return x;
}

// =================== single cooperative CSR-build kernel ===================
// grid = NBLK(256) blocks x 256 threads, all co-resident (1/CU).
// phase1: per-chunk LDS hist -> hmat[b][blk]
// phase2: per-bucket 256-scan of hmat row (in-place exscan), totals -> tsum[b]
// phase3: block 0 scans tsum -> bptr (exclusive bucket offsets)
// phase4: place packed (src<<SH)|(dst&BMSK) via LDS cursors (hmat-exscan + bptr)
// phase5: per-bucket node CSR: hist + scan -> row_ptr/cnt/dinv + col placement
__global__ __launch_bounds__(256) void k_build(
    const int* __restrict__ src, const int* __restrict__ dst,
    int* __restrict__ hmat, int* __restrict__ tsum, int* __restrict__ bptr,
    int* __restrict__ pairs, int* __restrict__ row_ptr, int* __restrict__ cnt,
    float* __restrict__ dinv, int* __restrict__ col,
    int n, int E, int NB, int chunk)
{
    cg::grid_group grid = cg::this_grid();
    int blk = blockIdx.x, t = threadIdx.x;
    int G = gridDim.x;
    int lane = t & 63, wv = t >> 6;
    __shared__ int h[MAXNB];
    __shared__ int ws[4];

    int beg = blk * chunk, end = beg + chunk; if (end > E) end = E;

    // ---- phase 1: per-chunk histogram ----
    for (int i = t; i < NB; i += 256) h[i] = 0;
    __syncthreads();
    for (int e = beg + t; e < end; e += 256) atomicAdd(&h[dst[e] >> SH], 1);
    __syncthreads();
    for (int i = t; i < NB; i += 256) hmat[i * NBLK + blk] = h[i];
    grid.sync();

    // ---- phase 2: per-bucket scan of its NBLK row ----
    for (int b = blk; b < NB; b += G) {
        int c = hmat[b * NBLK + t];
        int incl = wave_incl_scan(c, lane);
        if (lane == 63) ws[wv] = incl;
        __syncthreads();
        int wofs = 0;
#pragma unroll
        for (int w = 0; w < 4; ++w) if (w < wv) wofs += ws[w];
        hmat[b * NBLK + t] = wofs + incl - c;
        if (t == 255) tsum[b] = wofs + incl;
        __syncthreads();                      // protect ws for next bucket
    }
    grid.sync();

    // ---- phase 3: scan bucket totals -> bptr (block 0 only) ----
    if (blk == 0) {
        int base = t * 8;
        int local[8]; int s = 0;
#pragma unroll
        for (int k = 0; k < 8; ++k) { int i = base + k; int x = (i < NB) ? tsum[i] : 0; local[k] = s; s += x; }
        int incl = wave_incl_scan(s, lane);
        if (lane == 63) ws[wv] = incl;
        __syncthreads();
        int wofs = 0;
#pragma unroll
        for (int w = 0; w < 4; ++w) if (w < wv) wofs += ws[w];
        int texcl = wofs + incl - s;
#pragma unroll
        for (int k = 0; k < 8; ++k) { int i = base + k; if (i < NB) bptr[i] = texcl + local[k]; }
        if (t == 0) bptr[NB] = E;
    }
    grid.sync();

    // ---- phase 4: place into pairs (LDS cursors = bptr + per-chunk exscan) ----
    for (int i = t; i < NB; i += 256) h[i] = hmat[i * NBLK + blk] + bptr[i];
    __syncthreads();
    for (int e = beg + t; e < end; e += 256) {
        int s = src[e], d = dst[e];
        int off = atomicAdd(&h[d >> SH], 1);
        pairs[off] = (s << SH) | (d & BMSK);
    }
    grid.sync();

    // ---- phase 5: per-bucket node-level CSR ----
    for (int b = blk; b < NB; b += G) {
        int bbeg = bptr[b], bend = bptr[b + 1];
        h[t] = 0;
        __syncthreads();
        for (int j = bbeg + t; j < bend; j += 256) atomicAdd(&h[pairs[j] & BMSK], 1);
        __syncthreads();
        int c = h[t];
        int incl = wave_incl_scan(c, lane);
        if (lane == 63) ws[wv] = incl;
        __syncthreads();
        int wofs = 0;
#pragma unroll
        for (int w = 0; w < 4; ++w) if (w < wv) wofs += ws[w];
        int ex = wofs + incl - c;
        int node = (b << SH) + t;
        if (node < n) {
            row_ptr[node] = bbeg + ex;
            cnt[node] = c;
            dinv[node] = rsqrtf(1.0f + (float)c);
        }
        h[256 + t] = bbeg + ex;               // cursors in h[256..511]
        __syncthreads();
        for (int j = bbeg + t; j < bend; j += 256) {
            int pk = pairs[j];
            int p = atomicAdd(&h[256 + (pk & BMSK)], 1);
            col[p] = pk >> SH;
        }
        __syncthreads();
    }
}

// =================== GEMM1 via MFMA (f32 -> bf16 in-register, K=128) — round-16 validated ===================
__global__ __launch_bounds__(256) void k_mm1(
    const float* __restrict__ X, const float* __restrict__ W,
    const float* __restrict__ dinv, ushort_t* __restrict__ out, int n)
{
    __shared__ ushort_t wf[16 * 512];            // 16 KB: 16 frags x (64 lanes x 8 bf16)
    int t = threadIdx.x;
    for (int idx = t; idx < 128 * 64; idx += 256) {
        int k = idx >> 6, c = idx & 63;
        int f = ((k >> 5) << 2) | (c >> 4);
        int ln = (c & 15) | (((k >> 3) & 3) << 4);
        wf[f * 512 + ln * 8 + (k & 7)] = f2bf(W[idx]);
    }
    __syncthreads();

    int lane = t & 63, wv = t >> 6;
    int r16 = lane & 15, kg = lane >> 4;
    int tile = blockIdx.x * 4 + wv;              // one 16-row tile per wave
    int row = tile * 16 + r16;
    int r = (row < n) ? row : (n - 1);           // clamp: dup loads, stores guarded
    const float* pX = X + (size_t)r * 128 + kg * 8;

    // prefetch all 8 x-chunks (4 k-slices x 32 B) for MLP
    float4 u0a = *(const float4*)(pX + 0),   u0b = *(const float4*)(pX + 4);
    float4 u1a = *(const float4*)(pX + 32),  u1b = *(const float4*)(pX + 36);
    float4 u2a = *(const float4*)(pX + 64),  u2b = *(const float4*)(pX + 68);
    float4 u3a = *(const float4*)(pX + 96),  u3b = *(const float4*)(pX + 100);

    short8 b0, b1, b2, b3;
    PACK8(b0, u0a, u0b); PACK8(b1, u1a, u1b);
    PACK8(b2, u2a, u2b); PACK8(b3, u3a, u3b);

    short8 a0[4], a1[4], a2[4], a3[4];
#pragma unroll
    for (int f = 0; f < 4; ++f) {
        a0[f] = *(const short8*)(wf + (0 + f) * 512 + lane * 8);
        a1[f] = *(const short8*)(wf + (4 + f) * 512 + lane * 8);
        a2[f] = *(const short8*)(wf + (8 + f) * 512 + lane * 8);
        a3[f] = *(const short8*)(wf + (12 + f) * 512 + lane * 8);
    }

    f32x4 z = {0.f, 0.f, 0.f, 0.f};
    f32x4 acc[4];
#pragma unroll
    for (int f = 0; f < 4; ++f)
        acc[f] = __builtin_amdgcn_mfma_f32_16x16x32_bf16(a0[f], b0, z, 0, 0, 0);
#pragma unroll
    for (int f = 0; f < 4; ++f)
        acc[f] = __builtin_amdgcn_mfma_f32_16x16x32_bf16(a1[f], b1, acc[f], 0, 0, 0);
#pragma unroll
    for (int f = 0; f < 4; ++f)
        acc[f] = __builtin_amdgcn_mfma_f32_16x16x32_bf16(a2[f], b2, acc[f], 0, 0, 0);
#pragma unroll
    for (int f = 0; f < 4; ++f)
        acc[f] = __builtin_amdgcn_mfma_f32_16x16x32_bf16(a3[f], b3, acc[f], 0, 0, 0);

    if (row < n) {
        float di = dinv[row];
#pragma unroll
        for (int f = 0; f < 4; ++f) {
            ushort4 o;
            o.x = f2bf(acc[f][0] * di); o.y = f2bf(acc[f][1] * di);
            o.z = f2bf(acc[f][2] * di); o.w = f2bf(acc[f][3] * di);
            *(ushort4*)(out + (size_t)row * NF + f * 16 + kg * 4) = o;
        }
    }
}

// =================== GEMM2 via MFMA (bf16 x bf16 -> f32) — round-15 validated ===================
__global__ __launch_bounds__(256) void k_mm2(
    const ushort_t* __restrict__ Xb, const float* __restrict__ W,
    const float* __restrict__ dinv, ushort_t* __restrict__ out, int n)
{
    __shared__ ushort_t wf[8 * 512];             // 8 frags x (64 lanes x 8 bf16)
    int t = threadIdx.x;
    for (int idx = t; idx < 64 * 64; idx += 256) {
        int k = idx >> 6, c = idx & 63;
        int f = ((k >> 5) << 2) | (c >> 4);
        int ln = (c & 15) | (((k >> 3) & 3) << 4);
        wf[f * 512 + ln * 8 + (k & 7)] = f2bf(W[idx]);
    }
    __syncthreads();

    int lane = t & 63, wv = t >> 6;
    short8 af[8];
#pragma unroll
    for (int f = 0; f < 8; ++f)
        af[f] = *(const short8*)(wf + f * 512 + lane * 8);

    int r16 = lane & 15, kg = lane >> 4;
    int tile0 = blockIdx.x * 8 + wv * 2;
    int rowA = tile0 * 16 + r16;
    int rowB = rowA + 16;
    int rA = (rowA < n) ? rowA : (n - 1);        // clamp: dup loads, stores guarded
    int rB = (rowB < n) ? rowB : (n - 1);

    const ushort_t* pA = Xb + (size_t)rA * NF + kg * 8;
    const ushort_t* pB = Xb + (size_t)rB * NF + kg * 8;
    short8 bA0 = *(const short8*)(pA);           // ks=0
    short8 bA1 = *(const short8*)(pA + 32);      // ks=1
    short8 bB0 = *(const short8*)(pB);
    short8 bB1 = *(const short8*)(pB + 32);

    f32x4 z = {0.f, 0.f, 0.f, 0.f};
    f32x4 accA[4], accB[4];
#pragma unroll
    for (int f = 0; f < 4; ++f) {
        accA[f] = __builtin_amdgcn_mfma_f32_16x16x32_bf16(af[f], bA0, z, 0, 0, 0);
        accA[f] = __builtin_amdgcn_mfma_f32_16x16x32_bf16(af[4 + f], bA1, accA[f], 0, 0, 0);
        accB[f] = __builtin_amdgcn_mfma_f32_16x16x32_bf16(af[f], bB0, z, 0, 0, 0);
        accB[f] = __builtin_amdgcn_mfma_f32_16x16x32_bf16(af[4 + f], bB1, accB[f], 0, 0, 0);
    }

    if (rowA < n) {
        float di = dinv[rowA];
#pragma unroll
        for (int f = 0; f < 4; ++f) {
            ushort4 o;
            o.x = f2bf(accA[f][0] * di); o.y = f2bf(accA[f][1] * di);
            o.z = f2bf(accA[f][2] * di); o.w = f2bf(accA[f][3] * di);
            *(ushort4*)(out + (size_t)rowA * NF + f * 16 + kg * 4) = o;
        }
    }
    if (rowB < n) {
        float di = dinv[rowB];
#pragma unroll
        for (int f = 0; f < 4; ++f) {
            ushort4 o;
            o.x = f2bf(accB[f][0] * di); o.y = f2bf(accB[f][1] * di);
            o.z = f2bf(accB[f][2] * di); o.w = f2bf(accB[f][3] * di);
            *(ushort4*)(out + (size_t)rowB * NF + f * 16 + kg * 4) = o;
        }
    }
}

// =================== pull aggregation: one 16-lane group per dst node, bf16 rows ===================
// r = relu( dinv[d] * (hs[d] + sum_{s in N(d)} hs[s]) + bias )
// DECODE=0: write r row as bf16;  DECODE=1: write out[d] = r . Wd + bd (f32 scalar)
template<bool DECODE>
__global__ __launch_bounds__(256) void k_pull(
    const ushort_t* __restrict__ hs, const float* __restrict__ dinv,
    const int* __restrict__ row_ptr, const int* __restrict__ cnt,
    const int* __restrict__ col, const float* __restrict__ bias,
    const float* __restrict__ Wd, const float* __restrict__ bd,
    void* __restrict__ outv, int n)
{
    int d = blockIdx.x * 16 + (threadIdx.x >> 4);
    if (d >= n) return;
    int lt = threadIdx.x & 15;            // lane in group
    int fo = lt << 2;                     // feature offset (4 features/lane)
    int grpbase = threadIdx.x & 48;       // group base lane within wave
    int beg = row_ptr[d], deg = cnt[d];

    // self-loop (bf16 row, 8B/lane)
    uint2 sv = *((const uint2*)(hs + (size_t)d * NF) + lt);
    float4 acc = make_float4(bflo(sv.x), bfhi(sv.x), bflo(sv.y), bfhi(sv.y));

    for (int jb = 0; jb < deg; jb += 16) {
        int m = deg - jb; if (m > 16) m = 16;
        int idx = (lt < m) ? col[beg + jb + lt] : 0;
        uint2 v[16];
#pragma unroll
        for (int u = 0; u < 16; ++u) {
            int kk = (u < m) ? u : (m - 1);                  // clamp: dup loads hit L1
            int s = __shfl(idx, grpbase + kk, 64);
            v[u] = *((const uint2*)(hs + (size_t)s * NF) + lt);
        }
#pragma unroll
        for (int u = 0; u < 16; ++u) {
            if (u < m) {
                acc.x += bflo(v[u].x); acc.y += bfhi(v[u].x);
                acc.z += bflo(v[u].y); acc.w += bfhi(v[u].y);
            }
        }
    }

    float di = dinv[d];
    float4 bv = *(const float4*)(bias + fo);
    float rx = fmaxf(fmaf(acc.x, di, bv.x), 0.0f);
    float ry = fmaxf(fmaf(acc.y, di, bv.y), 0.0f);
    float rz = fmaxf(fmaf(acc.z, di, bv.z), 0.0f);
    float rw = fmaxf(fmaf(acc.w, di, bv.w), 0.0f);

    if (DECODE) {
        float4 wv = *(const float4*)(Wd + fo);
        float vsum = rx * wv.x + ry * wv.y + rz * wv.z + rw * wv.w;
#pragma unroll
        for (int o = 1; o < 16; o <<= 1) vsum += __shfl_xor(vsum, o, 64);
        if (lt == 0) ((float*)outv)[d] = vsum + bd[0];
    } else {
        ushort4 o;
        o.x = f2bf(rx); o.y = f2bf(ry); o.z = f2bf(rz); o.w = f2bf(rw);
        *(ushort4*)((ushort_t*)outv + (size_t)d * NF + fo) = o;
    }
}

extern "C" void kernel_launch(void* const* d_in, const int* in_sizes, int n_in,
                              void* d_out, int out_size, void* d_ws, size_t ws_size,
                              hipStream_t stream) {
    const float* x  = (const float*)d_in[0];
    const int*   ei = (const int*)d_in[1];
    const float* W1 = (const float*)d_in[2];
    const float* b1 = (const float*)d_in[3];
    const float* W2 = (const float*)d_in[4];
    const float* b2 = (const float*)d_in[5];
    const float* Wd = (const float*)d_in[6];
    const float* bd = (const float*)d_in[7];
    float* out = (float*)d_out;

    int n = in_sizes[0] / 128;
    int E = in_sizes[1] / 2;
    const int* src = ei;
    const int* dst = ei + E;

    int NB = (n + (1 << SH) - 1) >> SH;     // dst buckets of 256 nodes (~391)
    int chunk = (E + NBLK - 1) / NBLK;
    int ntot = NB * NBLK;
    int ntiles = (n + 15) / 16;             // 16-row MFMA tiles

    // workspace layout (4-byte elems) — pairs aliases bufH region (build ends before gemm1)
    float* dinv    = (float*)d_ws;                    // n
    float* bufH    = dinv + n;                        // 64n f32 region; holds bf16 hs
    float* bufA    = bufH + (size_t)n * NF;           // 64n f32 region; holds bf16 activations
    int*   counts  = (int*)(bufA + (size_t)n * NF);   // n
    int*   row_ptr = counts + n;                      // n
    int*   col     = row_ptr + n;                     // E
    int*   hmat    = col + E;                         // NB*NBLK
    int*   bptr    = hmat + ntot;                     // NB+1
    int*   tsum    = bptr + NB + 1;                   // NB
    int*   pairs   = (int*)bufH;                      // E (build lifetime only)
    ushort_t* hsb  = (ushort_t*)bufH;                 // 64n bf16 (post-build lifetime)
    ushort_t* actb = (ushort_t*)bufA;                 // 64n bf16 layer-1 activations

    // ---- fused cooperative CSR build (hist+scan+place+node-CSR+dinv) ----
    void* args[] = {(void*)&src, (void*)&dst, (void*)&hmat, (void*)&tsum, (void*)&bptr,
                    (void*)&pairs, (void*)&row_ptr, (void*)&counts, (void*)&dinv,
                    (void*)&col, (void*)&n, (void*)&E, (void*)&NB, (void*)&chunk};
    hipLaunchCooperativeKernel((const void*)k_build, dim3(NBLK), dim3(256), args, 0, stream);

    // ---- layer 1 (MFMA): hs = bf16((x @ W1) * dinv) ; pull (+b1, relu) -> bf16 acts ----
    k_mm1<<<(ntiles + 3) / 4, 256, 0, stream>>>(x, W1, dinv, hsb, n);
    k_pull<false><<<(n + 15) / 16, 256, 0, stream>>>(hsb, dinv, row_ptr, counts, col, b1,
                                                     Wd, bd, actb, n);

    // ---- layer 2 (MFMA): hs = bf16((acts @ W2) * dinv) ; pull (+b2, relu) + fused decode ----
    k_mm2<<<(ntiles + 7) / 8, 256, 0, stream>>>(actb, W2, dinv, hsb, n);
    k_pull<true><<<(n + 15) / 16, 256, 0, stream>>>(hsb, dinv, row_ptr, counts, col, b2,
                                                    Wd, bd, out, n);
}

// Round 20
// 141.728 us; speedup vs baseline: 1.9931x; 1.9931x over previous
//
#include <hip/hip_runtime.h>

#define NF 64      // hidden width (both layers)
#define NBLK 256   // chunks for the two-pass bucket sort
#define SH 8       // bucket = dst >> SH  (256 nodes per bucket)
#define BMSK 255
#define MAXNB 2048 // LDS histogram capacity (NB = ceil(n/256) <= 2048 -> n <= 524288)

typedef unsigned short ushort_t;
typedef __attribute__((ext_vector_type(8))) short short8;   // 8 bf16 = 4 VGPR (MFMA A/B frag)
typedef __attribute__((ext_vector_type(4))) float f32x4;    // MFMA C/D frag

__device__ inline ushort_t f2bf(float f) {               // RNE f32 -> bf16
    unsigned u = __float_as_uint(f);
    return (ushort_t)((u + 0x7fffu + ((u >> 16) & 1u)) >> 16);
}
__device__ inline float bfhi(unsigned x) { return __uint_as_float(x & 0xffff0000u); }
__device__ inline float bflo(unsigned x) { return __uint_as_float(x << 16); }

#define PACK8(b, ua, ub) \
    b[0] = (short)f2bf(ua.x); b[1] = (short)f2bf(ua.y); \
    b[2] = (short)f2bf(ua.z); b[3] = (short)f2bf(ua.w); \
    b[4] = (short)f2bf(ub.x); b[5] = (short)f2bf(ub.y); \
    b[6] = (short)f2bf(ub.z); b[7] = (short)f2bf(ub.w);

// =================== scan utilities ===================

__device__ inline int wave_incl_scan(int x, int lane) {
#pragma unroll
    for (int o = 1; o < 64; o <<= 1) { int y = __shfl_up(x, o, 64); if (lane >= o) x += y; }
    return x;
}

// 1024 elements per block (256 threads x 4); in-place safe
__global__ __launch_bounds__(256) void k_scan_a(const int* __restrict__ in, int* __restrict__ out,
                                                int* __restrict__ bsums, int n) {
    int t = threadIdx.x, lane = t & 63, wv = t >> 6;
    int base = blockIdx.x * 1024 + t * 4;
    int v[4]; int s = 0;
#pragma unroll
    for (int k = 0; k < 4; ++k) { int i = base + k; int x = (i < n) ? in[i] : 0; v[k] = s; s += x; }
    int incl = wave_incl_scan(s, lane);
    __shared__ int ws[4];
    if (lane == 63) ws[wv] = incl;
    __syncthreads();
    int wofs = 0;
#pragma unroll
    for (int w = 0; w < 4; ++w) if (w < wv) wofs += ws[w];
    int texcl = wofs + incl - s;
#pragma unroll
    for (int k = 0; k < 4; ++k) { int i = base + k; if (i < n) out[i] = texcl + v[k]; }
    if (t == 255) bsums[blockIdx.x] = wofs + incl;
}

// add block sums (prefix computed locally from raw bsums: <=2048 entries, one wave);
// also emit bucket pointers (bptr[b] = scanned hmat[b*NBLK], bptr[NB] = E)
__global__ __launch_bounds__(256) void k_scan_addb(int* __restrict__ data, const int* __restrict__ bsums,
                                                   int* __restrict__ bptr, int ntot, int E) {
    __shared__ int off_s;
    int t = threadIdx.x;
    int myChunk = (int)(blockIdx.x >> 2);          // this block's 1024-chunk index
    if (t < 64) {
        int s = 0;
        for (int i = t; i < myChunk; i += 64) s += bsums[i];
#pragma unroll
        for (int o = 32; o > 0; o >>= 1) s += __shfl_xor(s, o, 64);
        if (t == 0) off_s = s;
    }
    __syncthreads();
    int off = off_s;
    int i = blockIdx.x * 256 + t;
    if (i < ntot) {
        int v = data[i] + off;
        data[i] = v;
        if ((i & (NBLK - 1)) == 0) bptr[i / NBLK] = v;
    }
    if (i == 0) bptr[ntot / NBLK] = E;
}

// =================== contention-free bucket sort (bucket = dst >> SH, 256 nodes/bucket) ===================

__global__ __launch_bounds__(256) void k_histA(const int* __restrict__ dst, int* __restrict__ hmat,
                                               int E, int NB, int chunk) {
    __shared__ int h[MAXNB];
    int blk = blockIdx.x;
    for (int i = threadIdx.x; i < NB; i += 256) h[i] = 0;
    __syncthreads();
    int beg = blk * chunk, end = beg + chunk; if (end > E) end = E;
    for (int e = beg + threadIdx.x; e < end; e += 256) atomicAdd(&h[dst[e] >> SH], 1);
    __syncthreads();
    for (int i = threadIdx.x; i < NB; i += 256) hmat[i * NBLK + blk] = h[i];
}

__global__ __launch_bounds__(256) void k_placeB(const int* __restrict__ src, const int* __restrict__ dst,
                                                const int* __restrict__ hmat, int* __restrict__ pairs,
                                                int E, int NB, int chunk) {
    __shared__ int cur[MAXNB];
    int blk = blockIdx.x;
    for (int i = threadIdx.x; i < NB; i += 256) cur[i] = hmat[i * NBLK + blk];
    __syncthreads();
    int beg = blk * chunk, end = beg + chunk; if (end > E) end = E;
    for (int e = beg + threadIdx.x; e < end; e += 256) {
        int s = src[e], d = dst[e];
        int off = atomicAdd(&cur[d >> SH], 1);
        pairs[off] = (s << SH) | (d & BMSK);
    }
}

// =================== fused node-level CSR: hist + 256-scan + row_ptr/cnt/dinv + place ===================
// one block per 256-node bucket
__global__ __launch_bounds__(256) void k_csr(const int* __restrict__ bptr, const int* __restrict__ pairs,
                                             int* __restrict__ row_ptr, int* __restrict__ cnt,
                                             float* __restrict__ dinv, int* __restrict__ col, int n) {
    __shared__ int h[256];
    __shared__ int cur[256];
    __shared__ int ws[4];
    int b = blockIdx.x, t = threadIdx.x;
    h[t] = 0;
    __syncthreads();
    int beg = bptr[b], end = bptr[b + 1];
    for (int j = beg + t; j < end; j += 256) atomicAdd(&h[pairs[j] & BMSK], 1);
    __syncthreads();
    int c = h[t];
    int incl = wave_incl_scan(c, t & 63);
    if ((t & 63) == 63) ws[t >> 6] = incl;
    __syncthreads();
    int wofs = 0;
#pragma unroll
    for (int w = 0; w < 4; ++w) if (w < (t >> 6)) wofs += ws[w];
    int ex = wofs + incl - c;
    int node = (b << SH) + t;
    if (node < n) {
        row_ptr[node] = beg + ex;
        cnt[node] = c;
        dinv[node] = rsqrtf(1.0f + (float)c);
    }
    cur[t] = beg + ex;
    __syncthreads();
    for (int j = beg + t; j < end; j += 256) {
        int pk = pairs[j];
        int p = atomicAdd(&cur[pk & BMSK], 1);
        col[p] = pk >> SH;
    }
}

// =================== GEMM1 via MFMA (f32 -> bf16 in-register, K=128) — round-16 validated ===================
__global__ __launch_bounds__(256) void k_mm1(
    const float* __restrict__ X, const float* __restrict__ W,
    const float* __restrict__ dinv, ushort_t* __restrict__ out, int n)
{
    __shared__ ushort_t wf[16 * 512];            // 16 KB: 16 frags x (64 lanes x 8 bf16)
    int t = threadIdx.x;
    for (int idx = t; idx < 128 * 64; idx += 256) {
        int k = idx >> 6, c = idx & 63;
        int f = ((k >> 5) << 2) | (c >> 4);
        int ln = (c & 15) | (((k >> 3) & 3) << 4);
        wf[f * 512 + ln * 8 + (k & 7)] = f2bf(W[idx]);
    }
    __syncthreads();

    int lane = t & 63, wv = t >> 6;
    int r16 = lane & 15, kg = lane >> 4;
    int tile = blockIdx.x * 4 + wv;              // one 16-row tile per wave
    int row = tile * 16 + r16;
    int r = (row < n) ? row : (n - 1);           // clamp: dup loads, stores guarded
    const float* pX = X + (size_t)r * 128 + kg * 8;

    // prefetch all 8 x-chunks (4 k-slices x 32 B) for MLP
    float4 u0a = *(const float4*)(pX + 0),   u0b = *(const float4*)(pX + 4);
    float4 u1a = *(const float4*)(pX + 32),  u1b = *(const float4*)(pX + 36);
    float4 u2a = *(const float4*)(pX + 64),  u2b = *(const float4*)(pX + 68);
    float4 u3a = *(const float4*)(pX + 96),  u3b = *(const float4*)(pX + 100);

    short8 b0, b1, b2, b3;
    PACK8(b0, u0a, u0b); PACK8(b1, u1a, u1b);
    PACK8(b2, u2a, u2b); PACK8(b3, u3a, u3b);

    short8 a0[4], a1[4], a2[4], a3[4];
#pragma unroll
    for (int f = 0; f < 4; ++f) {
        a0[f] = *(const short8*)(wf + (0 + f) * 512 + lane * 8);
        a1[f] = *(const short8*)(wf + (4 + f) * 512 + lane * 8);
        a2[f] = *(const short8*)(wf + (8 + f) * 512 + lane * 8);
        a3[f] = *(const short8*)(wf + (12 + f) * 512 + lane * 8);
    }

    f32x4 z = {0.f, 0.f, 0.f, 0.f};
    f32x4 acc[4];
#pragma unroll
    for (int f = 0; f < 4; ++f)
        acc[f] = __builtin_amdgcn_mfma_f32_16x16x32_bf16(a0[f], b0, z, 0, 0, 0);
#pragma unroll
    for (int f = 0; f < 4; ++f)
        acc[f] = __builtin_amdgcn_mfma_f32_16x16x32_bf16(a1[f], b1, acc[f], 0, 0, 0);
#pragma unroll
    for (int f = 0; f < 4; ++f)
        acc[f] = __builtin_amdgcn_mfma_f32_16x16x32_bf16(a2[f], b2, acc[f], 0, 0, 0);
#pragma unroll
    for (int f = 0; f < 4; ++f)
        acc[f] = __builtin_amdgcn_mfma_f32_16x16x32_bf16(a3[f], b3, acc[f], 0, 0, 0);

    if (row < n) {
        float di = dinv[row];
#pragma unroll
        for (int f = 0; f < 4; ++f) {
            ushort4 o;
            o.x = f2bf(acc[f][0] * di); o.y = f2bf(acc[f][1] * di);
            o.z = f2bf(acc[f][2] * di); o.w = f2bf(acc[f][3] * di);
            *(ushort4*)(out + (size_t)row * NF + f * 16 + kg * 4) = o;
        }
    }
}

// =================== GEMM2 via MFMA (bf16 x bf16 -> f32) — round-15 validated ===================
__global__ __launch_bounds__(256) void k_mm2(
    const ushort_t* __restrict__ Xb, const float* __restrict__ W,
    const float* __restrict__ dinv, ushort_t* __restrict__ out, int n)
{
    __shared__ ushort_t wf[8 * 512];             // 8 frags x (64 lanes x 8 bf16)
    int t = threadIdx.x;
    for (int idx = t; idx < 64 * 64; idx += 256) {
        int k = idx >> 6, c = idx & 63;
        int f = ((k >> 5) << 2) | (c >> 4);
        int ln = (c & 15) | (((k >> 3) & 3) << 4);
        wf[f * 512 + ln * 8 + (k & 7)] = f2bf(W[idx]);
    }
    __syncthreads();

    int lane = t & 63, wv = t >> 6;
    short8 af[8];
#pragma unroll
    for (int f = 0; f < 8; ++f)
        af[f] = *(const short8*)(wf + f * 512 + lane * 8);

    int r16 = lane & 15, kg = lane >> 4;
    int tile0 = blockIdx.x * 8 + wv * 2;
    int rowA = tile0 * 16 + r16;
    int rowB = rowA + 16;
    int rA = (rowA < n) ? rowA : (n - 1);        // clamp: dup loads, stores guarded
    int rB = (rowB < n) ? rowB : (n - 1);

    const ushort_t* pA = Xb + (size_t)rA * NF + kg * 8;
    const ushort_t* pB = Xb + (size_t)rB * NF + kg * 8;
    short8 bA0 = *(const short8*)(pA);           // ks=0
    short8 bA1 = *(const short8*)(pA + 32);      // ks=1
    short8 bB0 = *(const short8*)(pB);
    short8 bB1 = *(const short8*)(pB + 32);

    f32x4 z = {0.f, 0.f, 0.f, 0.f};
    f32x4 accA[4], accB[4];
#pragma unroll
    for (int f = 0; f < 4; ++f) {
        accA[f] = __builtin_amdgcn_mfma_f32_16x16x32_bf16(af[f], bA0, z, 0, 0, 0);
        accA[f] = __builtin_amdgcn_mfma_f32_16x16x32_bf16(af[4 + f], bA1, accA[f], 0, 0, 0);
        accB[f] = __builtin_amdgcn_mfma_f32_16x16x32_bf16(af[f], bB0, z, 0, 0, 0);
        accB[f] = __builtin_amdgcn_mfma_f32_16x16x32_bf16(af[4 + f], bB1, accB[f], 0, 0, 0);
    }

    if (rowA < n) {
        float di = dinv[rowA];
#pragma unroll
        for (int f = 0; f < 4; ++f) {
            ushort4 o;
            o.x = f2bf(accA[f][0] * di); o.y = f2bf(accA[f][1] * di);
            o.z = f2bf(accA[f][2] * di); o.w = f2bf(accA[f][3] * di);
            *(ushort4*)(out + (size_t)rowA * NF + f * 16 + kg * 4) = o;
        }
    }
    if (rowB < n) {
        float di = dinv[rowB];
#pragma unroll
        for (int f = 0; f < 4; ++f) {
            ushort4 o;
            o.x = f2bf(accB[f][0] * di); o.y = f2bf(accB[f][1] * di);
            o.z = f2bf(accB[f][2] * di); o.w = f2bf(accB[f][3] * di);
            *(ushort4*)(out + (size_t)rowB * NF + f * 16 + kg * 4) = o;
        }
    }
}

// =================== pull aggregation: one 16-lane group per dst node, bf16 rows ===================
// r = relu( dinv[d] * (hs[d] + sum_{s in N(d)} hs[s]) + bias )
// DECODE=0: write r row as bf16;  DECODE=1: write out[d] = r . Wd + bd (f32 scalar)
template<bool DECODE>
__global__ __launch_bounds__(256) void k_pull(
    const ushort_t* __restrict__ hs, const float* __restrict__ dinv,
    const int* __restrict__ row_ptr, const int* __restrict__ cnt,
    const int* __restrict__ col, const float* __restrict__ bias,
    const float* __restrict__ Wd, const float* __restrict__ bd,
    void* __restrict__ outv, int n)
{
    int d = blockIdx.x * 16 + (threadIdx.x >> 4);
    if (d >= n) return;
    int lt = threadIdx.x & 15;            // lane in group
    int fo = lt << 2;                     // feature offset (4 features/lane)
    int grpbase = threadIdx.x & 48;       // group base lane within wave
    int beg = row_ptr[d], deg = cnt[d];

    // self-loop (bf16 row, 8B/lane)
    uint2 sv = *((const uint2*)(hs + (size_t)d * NF) + lt);
    float4 acc = make_float4(bflo(sv.x), bfhi(sv.x), bflo(sv.y), bfhi(sv.y));

    for (int jb = 0; jb < deg; jb += 16) {
        int m = deg - jb; if (m > 16) m = 16;
        int idx = (lt < m) ? col[beg + jb + lt] : 0;
        uint2 v[16];
#pragma unroll
        for (int u = 0; u < 16; ++u) {
            int kk = (u < m) ? u : (m - 1);                  // clamp: dup loads hit L1
            int s = __shfl(idx, grpbase + kk, 64);
            v[u] = *((const uint2*)(hs + (size_t)s * NF) + lt);
        }
#pragma unroll
        for (int u = 0; u < 16; ++u) {
            if (u < m) {
                acc.x += bflo(v[u].x); acc.y += bfhi(v[u].x);
                acc.z += bflo(v[u].y); acc.w += bfhi(v[u].y);
            }
        }
    }

    float di = dinv[d];
    float4 bv = *(const float4*)(bias + fo);
    float rx = fmaxf(fmaf(acc.x, di, bv.x), 0.0f);
    float ry = fmaxf(fmaf(acc.y, di, bv.y), 0.0f);
    float rz = fmaxf(fmaf(acc.z, di, bv.z), 0.0f);
    float rw = fmaxf(fmaf(acc.w, di, bv.w), 0.0f);

    if (DECODE) {
        float4 wv = *(const float4*)(Wd + fo);
        float vsum = rx * wv.x + ry * wv.y + rz * wv.z + rw * wv.w;
#pragma unroll
        for (int o = 1; o < 16; o <<= 1) vsum += __shfl_xor(vsum, o, 64);
        if (lt == 0) ((float*)outv)[d] = vsum + bd[0];
    } else {
        ushort4 o;
        o.x = f2bf(rx); o.y = f2bf(ry); o.z = f2bf(rz); o.w = f2bf(rw);
        *(ushort4*)((ushort_t*)outv + (size_t)d * NF + fo) = o;
    }
}

extern "C" void kernel_launch(void* const* d_in, const int* in_sizes, int n_in,
                              void* d_out, int out_size, void* d_ws, size_t ws_size,
                              hipStream_t stream) {
    const float* x  = (const float*)d_in[0];
    const int*   ei = (const int*)d_in[1];
    const float* W1 = (const float*)d_in[2];
    const float* b1 = (const float*)d_in[3];
    const float* W2 = (const float*)d_in[4];
    const float* b2 = (const float*)d_in[5];
    const float* Wd = (const float*)d_in[6];
    const float* bd = (const float*)d_in[7];
    float* out = (float*)d_out;

    int n = in_sizes[0] / 128;
    int E = in_sizes[1] / 2;
    const int* src = ei;
    const int* dst = ei + E;

    int NB = (n + (1 << SH) - 1) >> SH;     // dst buckets of 256 nodes (~391)
    int chunk = (E + NBLK - 1) / NBLK;
    int ntot = NB * NBLK;                   // hist matrix size (~100k)
    int nsb = (ntot + 1023) / 1024;         // scan blocks over hmat (<= 2048)
    int ntiles = (n + 15) / 16;             // 16-row MFMA tiles

    // workspace layout (4-byte elems) — pairs aliases bufH region (build ends before gemm1)
    float* dinv    = (float*)d_ws;                    // n
    float* bufH    = dinv + n;                        // 64n f32 region; holds bf16 hs
    float* bufA    = bufH + (size_t)n * NF;           // 64n f32 region; holds bf16 activations
    int*   counts  = (int*)(bufA + (size_t)n * NF);   // n
    int*   row_ptr = counts + n;                      // n
    int*   col     = row_ptr + n;                     // E
    int*   hmat    = col + E;                         // NB*NBLK
    int*   bptr    = hmat + ntot;                     // NB+1
    int*   bsums   = bptr + NB + 1;                   // <=2048
    int*   pairs   = (int*)bufH;                      // E (build lifetime only)
    ushort_t* hsb  = (ushort_t*)bufH;                 // 64n bf16 (post-build lifetime)
    ushort_t* actb = (ushort_t*)bufA;                 // 64n bf16 layer-1 activations

    // ---- bucket sort by dst (contention-free, full-line write segments) ----
    k_histA<<<NBLK, 256, 0, stream>>>(dst, hmat, E, NB, chunk);
    k_scan_a<<<nsb, 256, 0, stream>>>(hmat, hmat, bsums, ntot);
    k_scan_addb<<<(ntot + 255) / 256, 256, 0, stream>>>(hmat, bsums, bptr, ntot, E);
    k_placeB<<<NBLK, 256, 0, stream>>>(src, dst, hmat, pairs, E, NB, chunk);

    // ---- fused node-level CSR + dinv (one block per 256-node bucket) ----
    k_csr<<<NB, 256, 0, stream>>>(bptr, pairs, row_ptr, counts, dinv, col, n);

    // ---- layer 1 (MFMA): hs = bf16((x @ W1) * dinv) ; pull (+b1, relu) -> bf16 acts ----
    k_mm1<<<(ntiles + 3) / 4, 256, 0, stream>>>(x, W1, dinv, hsb, n);
    k_pull<false><<<(n + 15) / 16, 256, 0, stream>>>(hsb, dinv, row_ptr, counts, col, b1,
                                                     Wd, bd, actb, n);

    // ---- layer 2 (MFMA): hs = bf16((acts @ W2) * dinv) ; pull (+b2, relu) + fused decode ----
    k_mm2<<<(ntiles + 7) / 8, 256, 0, stream>>>(actb, W2, dinv, hsb, n);
    k_pull<true><<<(n + 15) / 16, 256, 0, stream>>>(hsb, dinv, row_ptr, counts, col, b2,
                                                    Wd, bd, out, n);
}

// Round 21
// 133.986 us; speedup vs baseline: 2.1082x; 1.0578x over previous
//
#include <hip/hip_runtime.h>

#define NF 64      // hidden width (both layers)
#define NBLK 256   // chunks for the two-pass bucket sort
#define SH 8       // bucket = dst >> SH  (256 nodes per bucket)
#define BMSK 255
#define MAXNB 2048 // LDS histogram capacity (NB = ceil(n/256) <= 2048 -> n <= 524288)

typedef unsigned short ushort_t;
typedef __attribute__((ext_vector_type(8))) short short8;   // 8 bf16 = 4 VGPR (MFMA A/B frag)
typedef __attribute__((ext_vector_type(4))) float f32x4;    // MFMA C/D frag

__device__ inline ushort_t f2bf(float f) {               // RNE f32 -> bf16
    unsigned u = __float_as_uint(f);
    return (ushort_t)((u + 0x7fffu + ((u >> 16) & 1u)) >> 16);
}
__device__ inline float bfhi(unsigned x) { return __uint_as_float(x & 0xffff0000u); }
__device__ inline float bflo(unsigned x) { return __uint_as_float(x << 16); }

#define PACK8(b, ua, ub) \
    b[0] = (short)f2bf(ua.x); b[1] = (short)f2bf(ua.y); \
    b[2] = (short)f2bf(ua.z); b[3] = (short)f2bf(ua.w); \
    b[4] = (short)f2bf(ub.x); b[5] = (short)f2bf(ub.y); \
    b[6] = (short)f2bf(ub.z); b[7] = (short)f2bf(ub.w);

// =================== scan utilities ===================

__device__ inline int wave_incl_scan(int x, int lane) {
#pragma unroll
    for (int o = 1; o < 64; o <<= 1) { int y = __shfl_up(x, o, 64); if (lane >= o) x += y; }
    return x;
}

// 1024 elements per block (256 threads x 4); in-place safe
__global__ __launch_bounds__(256) void k_scan_a(const int* __restrict__ in, int* __restrict__ out,
                                                int* __restrict__ bsums, int n) {
    int t = threadIdx.x, lane = t & 63, wv = t >> 6;
    int base = blockIdx.x * 1024 + t * 4;
    int v[4]; int s = 0;
#pragma unroll
    for (int k = 0; k < 4; ++k) { int i = base + k; int x = (i < n) ? in[i] : 0; v[k] = s; s += x; }
    int incl = wave_incl_scan(s, lane);
    __shared__ int ws[4];
    if (lane == 63) ws[wv] = incl;
    __syncthreads();
    int wofs = 0;
#pragma unroll
    for (int w = 0; w < 4; ++w) if (w < wv) wofs += ws[w];
    int texcl = wofs + incl - s;
#pragma unroll
    for (int k = 0; k < 4; ++k) { int i = base + k; if (i < n) out[i] = texcl + v[k]; }
    if (t == 255) bsums[blockIdx.x] = wofs + incl;
}

// add block sums (prefix computed locally from raw bsums: <=2048 entries, one wave);
// also emit bucket pointers (bptr[b] = scanned hmat[b*NBLK], bptr[NB] = E)
__global__ __launch_bounds__(256) void k_scan_addb(int* __restrict__ data, const int* __restrict__ bsums,
                                                   int* __restrict__ bptr, int ntot, int E) {
    __shared__ int off_s;
    int t = threadIdx.x;
    int myChunk = (int)(blockIdx.x >> 2);          // this block's 1024-chunk index
    if (t < 64) {
        int s = 0;
        for (int i = t; i < myChunk; i += 64) s += bsums[i];
#pragma unroll
        for (int o = 32; o > 0; o >>= 1) s += __shfl_xor(s, o, 64);
        if (t == 0) off_s = s;
    }
    __syncthreads();
    int off = off_s;
    int i = blockIdx.x * 256 + t;
    if (i < ntot) {
        int v = data[i] + off;
        data[i] = v;
        if ((i & (NBLK - 1)) == 0) bptr[i / NBLK] = v;
    }
    if (i == 0) bptr[ntot / NBLK] = E;
}

// =================== contention-free bucket sort (bucket = dst >> SH, 256 nodes/bucket) ===================

__global__ __launch_bounds__(256) void k_histA(const int* __restrict__ dst, int* __restrict__ hmat,
                                               int E, int NB, int chunk) {
    __shared__ int h[MAXNB];
    int blk = blockIdx.x;
    for (int i = threadIdx.x; i < NB; i += 256) h[i] = 0;
    __syncthreads();
    int beg = blk * chunk, end = beg + chunk; if (end > E) end = E;
    for (int e = beg + threadIdx.x; e < end; e += 256) atomicAdd(&h[dst[e] >> SH], 1);
    __syncthreads();
    for (int i = threadIdx.x; i < NB; i += 256) hmat[i * NBLK + blk] = h[i];
}

__global__ __launch_bounds__(256) void k_placeB(const int* __restrict__ src, const int* __restrict__ dst,
                                                const int* __restrict__ hmat, int* __restrict__ pairs,
                                                int E, int NB, int chunk) {
    __shared__ int cur[MAXNB];
    int blk = blockIdx.x;
    for (int i = threadIdx.x; i < NB; i += 256) cur[i] = hmat[i * NBLK + blk];
    __syncthreads();
    int beg = blk * chunk, end = beg + chunk; if (end > E) end = E;
    for (int e = beg + threadIdx.x; e < end; e += 256) {
        int s = src[e], d = dst[e];
        int off = atomicAdd(&cur[d >> SH], 1);
        pairs[off] = (s << SH) | (d & BMSK);
    }
}

// =================== fused node-level CSR: hist + 256-scan + row_ptr/cnt/dinv + place ===================
// one block per 256-node bucket
__global__ __launch_bounds__(256) void k_csr(const int* __restrict__ bptr, const int* __restrict__ pairs,
                                             int* __restrict__ row_ptr, int* __restrict__ cnt,
                                             float* __restrict__ dinv, int* __restrict__ col, int n) {
    __shared__ int h[256];
    __shared__ int cur[256];
    __shared__ int ws[4];
    int b = blockIdx.x, t = threadIdx.x;
    h[t] = 0;
    __syncthreads();
    int beg = bptr[b], end = bptr[b + 1];
    for (int j = beg + t; j < end; j += 256) atomicAdd(&h[pairs[j] & BMSK], 1);
    __syncthreads();
    int c = h[t];
    int incl = wave_incl_scan(c, t & 63);
    if ((t & 63) == 63) ws[t >> 6] = incl;
    __syncthreads();
    int wofs = 0;
#pragma unroll
    for (int w = 0; w < 4; ++w) if (w < (t >> 6)) wofs += ws[w];
    int ex = wofs + incl - c;
    int node = (b << SH) + t;
    if (node < n) {
        row_ptr[node] = beg + ex;
        cnt[node] = c;
        dinv[node] = rsqrtf(1.0f + (float)c);
    }
    cur[t] = beg + ex;
    __syncthreads();
    for (int j = beg + t; j < end; j += 256) {
        int pk = pairs[j];
        int p = atomicAdd(&cur[pk & BMSK], 1);
        col[p] = pk >> SH;
    }
}

// =================== GEMM1 via MFMA (f32 -> bf16 in-register, K=128) — round-16 validated ===================
__global__ __launch_bounds__(256) void k_mm1(
    const float* __restrict__ X, const float* __restrict__ W,
    const float* __restrict__ dinv, ushort_t* __restrict__ out, int n)
{
    __shared__ ushort_t wf[16 * 512];            // 16 KB: 16 frags x (64 lanes x 8 bf16)
    int t = threadIdx.x;
    for (int idx = t; idx < 128 * 64; idx += 256) {
        int k = idx >> 6, c = idx & 63;
        int f = ((k >> 5) << 2) | (c >> 4);
        int ln = (c & 15) | (((k >> 3) & 3) << 4);
        wf[f * 512 + ln * 8 + (k & 7)] = f2bf(W[idx]);
    }
    __syncthreads();

    int lane = t & 63, wv = t >> 6;
    int r16 = lane & 15, kg = lane >> 4;
    int tile = blockIdx.x * 4 + wv;              // one 16-row tile per wave
    int row = tile * 16 + r16;
    int r = (row < n) ? row : (n - 1);           // clamp: dup loads, stores guarded
    const float* pX = X + (size_t)r * 128 + kg * 8;

    // prefetch all 8 x-chunks (4 k-slices x 32 B) for MLP
    float4 u0a = *(const float4*)(pX + 0),   u0b = *(const float4*)(pX + 4);
    float4 u1a = *(const float4*)(pX + 32),  u1b = *(const float4*)(pX + 36);
    float4 u2a = *(const float4*)(pX + 64),  u2b = *(const float4*)(pX + 68);
    float4 u3a = *(const float4*)(pX + 96),  u3b = *(const float4*)(pX + 100);

    short8 b0, b1, b2, b3;
    PACK8(b0, u0a, u0b); PACK8(b1, u1a, u1b);
    PACK8(b2, u2a, u2b); PACK8(b3, u3a, u3b);

    short8 a0[4], a1[4], a2[4], a3[4];
#pragma unroll
    for (int f = 0; f < 4; ++f) {
        a0[f] = *(const short8*)(wf + (0 + f) * 512 + lane * 8);
        a1[f] = *(const short8*)(wf + (4 + f) * 512 + lane * 8);
        a2[f] = *(const short8*)(wf + (8 + f) * 512 + lane * 8);
        a3[f] = *(const short8*)(wf + (12 + f) * 512 + lane * 8);
    }

    f32x4 z = {0.f, 0.f, 0.f, 0.f};
    f32x4 acc[4];
#pragma unroll
    for (int f = 0; f < 4; ++f)
        acc[f] = __builtin_amdgcn_mfma_f32_16x16x32_bf16(a0[f], b0, z, 0, 0, 0);
#pragma unroll
    for (int f = 0; f < 4; ++f)
        acc[f] = __builtin_amdgcn_mfma_f32_16x16x32_bf16(a1[f], b1, acc[f], 0, 0, 0);
#pragma unroll
    for (int f = 0; f < 4; ++f)
        acc[f] = __builtin_amdgcn_mfma_f32_16x16x32_bf16(a2[f], b2, acc[f], 0, 0, 0);
#pragma unroll
    for (int f = 0; f < 4; ++f)
        acc[f] = __builtin_amdgcn_mfma_f32_16x16x32_bf16(a3[f], b3, acc[f], 0, 0, 0);

    if (row < n) {
        float di = dinv[row];
#pragma unroll
        for (int f = 0; f < 4; ++f) {
            ushort4 o;
            o.x = f2bf(acc[f][0] * di); o.y = f2bf(acc[f][1] * di);
            o.z = f2bf(acc[f][2] * di); o.w = f2bf(acc[f][3] * di);
            *(ushort4*)(out + (size_t)row * NF + f * 16 + kg * 4) = o;
        }
    }
}

// =================== fused pull1 + GEMM2 ===================
// Block = 256 threads = 16 dst nodes = one 16-row MFMA tile.
// Phase A (pull): act_row(d) = relu(dinv[d]*(hs[d]+sum hs[src])+b1) -> LDS tile (bf16)
// Phase B (mm2):  hs2[d] = bf16((act @ W2) * dinv[d]) via the round-15-validated mapping;
//                 wave wv computes column slab [wv*16, wv*16+16).
__global__ __launch_bounds__(256) void k_pullmm(
    const ushort_t* __restrict__ hs, const float* __restrict__ dinv,
    const int* __restrict__ row_ptr, const int* __restrict__ cnt,
    const int* __restrict__ col, const float* __restrict__ bias,
    const float* __restrict__ W, ushort_t* __restrict__ out, int n)
{
    __shared__ ushort_t wf[8 * 512];             // W2 frags (8 KB), k_mm2 swizzle
    __shared__ ushort_t act[16][64];             // activation tile (2 KB)
    int t = threadIdx.x;
    for (int idx = t; idx < 64 * 64; idx += 256) {
        int k = idx >> 6, c = idx & 63;
        int f = ((k >> 5) << 2) | (c >> 4);
        int ln = (c & 15) | (((k >> 3) & 3) << 4);
        wf[f * 512 + ln * 8 + (k & 7)] = f2bf(W[idx]);
    }

    // ---- phase A: pull (one 16-lane group per node) ----
    int d = blockIdx.x * 16 + (t >> 4);
    int lt = t & 15;
    int fo = lt << 2;
    int grpbase = t & 48;
    float rx = 0.f, ry = 0.f, rz = 0.f, rw = 0.f;
    if (d < n) {
        uint2 sv = *((const uint2*)(hs + (size_t)d * NF) + lt);
        float4 acc = make_float4(bflo(sv.x), bfhi(sv.x), bflo(sv.y), bfhi(sv.y));
        int beg = row_ptr[d], deg = cnt[d];
        for (int jb = 0; jb < deg; jb += 16) {
            int m = deg - jb; if (m > 16) m = 16;
            int idx = (lt < m) ? col[beg + jb + lt] : 0;
            uint2 v[16];
#pragma unroll
            for (int u = 0; u < 16; ++u) {
                int kk = (u < m) ? u : (m - 1);              // clamp: dup loads hit L1
                int s = __shfl(idx, grpbase + kk, 64);
                v[u] = *((const uint2*)(hs + (size_t)s * NF) + lt);
            }
#pragma unroll
            for (int u = 0; u < 16; ++u) {
                if (u < m) {
                    acc.x += bflo(v[u].x); acc.y += bfhi(v[u].x);
                    acc.z += bflo(v[u].y); acc.w += bfhi(v[u].y);
                }
            }
        }
        float di = dinv[d];
        float4 bv = *(const float4*)(bias + fo);
        rx = fmaxf(fmaf(acc.x, di, bv.x), 0.0f);
        ry = fmaxf(fmaf(acc.y, di, bv.y), 0.0f);
        rz = fmaxf(fmaf(acc.z, di, bv.z), 0.0f);
        rw = fmaxf(fmaf(acc.w, di, bv.w), 0.0f);
    }
    {
        ushort4 o;
        o.x = f2bf(rx); o.y = f2bf(ry); o.z = f2bf(rz); o.w = f2bf(rw);
        *(ushort4*)(&act[t >> 4][fo]) = o;
    }
    __syncthreads();

    // ---- phase B: MFMA (wave wv -> columns [wv*16, wv*16+16)) ----
    int lane = t & 63, wv = t >> 6;
    int r16 = lane & 15, kg = lane >> 4;
    short8 aflo = *(const short8*)(wf + wv * 512 + lane * 8);
    short8 afhi = *(const short8*)(wf + (4 + wv) * 512 + lane * 8);
    short8 bb0 = *(const short8*)(&act[r16][kg * 8]);
    short8 bb1 = *(const short8*)(&act[r16][kg * 8 + 32]);

    f32x4 z = {0.f, 0.f, 0.f, 0.f};
    f32x4 acc2 = __builtin_amdgcn_mfma_f32_16x16x32_bf16(aflo, bb0, z, 0, 0, 0);
    acc2 = __builtin_amdgcn_mfma_f32_16x16x32_bf16(afhi, bb1, acc2, 0, 0, 0);

    int row = blockIdx.x * 16 + r16;
    if (row < n) {
        float di = dinv[row];
        ushort4 o;
        o.x = f2bf(acc2[0] * di); o.y = f2bf(acc2[1] * di);
        o.z = f2bf(acc2[2] * di); o.w = f2bf(acc2[3] * di);
        *(ushort4*)(out + (size_t)row * NF + wv * 16 + kg * 4) = o;
    }
}

// =================== pull2 + fused decode: out[d] = relu(dinv*(...)+b2) . Wd + bd ===================
__global__ __launch_bounds__(256) void k_pull2(
    const ushort_t* __restrict__ hs, const float* __restrict__ dinv,
    const int* __restrict__ row_ptr, const int* __restrict__ cnt,
    const int* __restrict__ col, const float* __restrict__ bias,
    const float* __restrict__ Wd, const float* __restrict__ bd,
    float* __restrict__ outv, int n)
{
    int d = blockIdx.x * 16 + (threadIdx.x >> 4);
    if (d >= n) return;
    int lt = threadIdx.x & 15;            // lane in group
    int fo = lt << 2;                     // feature offset (4 features/lane)
    int grpbase = threadIdx.x & 48;       // group base lane within wave
    int beg = row_ptr[d], deg = cnt[d];

    // self-loop (bf16 row, 8B/lane)
    uint2 sv = *((const uint2*)(hs + (size_t)d * NF) + lt);
    float4 acc = make_float4(bflo(sv.x), bfhi(sv.x), bflo(sv.y), bfhi(sv.y));

    for (int jb = 0; jb < deg; jb += 16) {
        int m = deg - jb; if (m > 16) m = 16;
        int idx = (lt < m) ? col[beg + jb + lt] : 0;
        uint2 v[16];
#pragma unroll
        for (int u = 0; u < 16; ++u) {
            int kk = (u < m) ? u : (m - 1);                  // clamp: dup loads hit L1
            int s = __shfl(idx, grpbase + kk, 64);
            v[u] = *((const uint2*)(hs + (size_t)s * NF) + lt);
        }
#pragma unroll
        for (int u = 0; u < 16; ++u) {
            if (u < m) {
                acc.x += bflo(v[u].x); acc.y += bfhi(v[u].x);
                acc.z += bflo(v[u].y); acc.w += bfhi(v[u].y);
            }
        }
    }

    float di = dinv[d];
    float4 bv = *(const float4*)(bias + fo);
    float rx = fmaxf(fmaf(acc.x, di, bv.x), 0.0f);
    float ry = fmaxf(fmaf(acc.y, di, bv.y), 0.0f);
    float rz = fmaxf(fmaf(acc.z, di, bv.z), 0.0f);
    float rw = fmaxf(fmaf(acc.w, di, bv.w), 0.0f);

    float4 wv = *(const float4*)(Wd + fo);
    float vsum = rx * wv.x + ry * wv.y + rz * wv.z + rw * wv.w;
#pragma unroll
    for (int o = 1; o < 16; o <<= 1) vsum += __shfl_xor(vsum, o, 64);
    if (lt == 0) outv[d] = vsum + bd[0];
}

extern "C" void kernel_launch(void* const* d_in, const int* in_sizes, int n_in,
                              void* d_out, int out_size, void* d_ws, size_t ws_size,
                              hipStream_t stream) {
    const float* x  = (const float*)d_in[0];
    const int*   ei = (const int*)d_in[1];
    const float* W1 = (const float*)d_in[2];
    const float* b1 = (const float*)d_in[3];
    const float* W2 = (const float*)d_in[4];
    const float* b2 = (const float*)d_in[5];
    const float* Wd = (const float*)d_in[6];
    const float* bd = (const float*)d_in[7];
    float* out = (float*)d_out;

    int n = in_sizes[0] / 128;
    int E = in_sizes[1] / 2;
    const int* src = ei;
    const int* dst = ei + E;

    int NB = (n + (1 << SH) - 1) >> SH;     // dst buckets of 256 nodes (~391)
    int chunk = (E + NBLK - 1) / NBLK;
    int ntot = NB * NBLK;                   // hist matrix size (~100k)
    int nsb = (ntot + 1023) / 1024;         // scan blocks over hmat (<= 2048)
    int ntiles = (n + 15) / 16;             // 16-row MFMA tiles

    // workspace layout (4-byte elems) — pairs aliases bufH region (build ends before gemm1)
    float* dinv    = (float*)d_ws;                    // n
    float* bufH    = dinv + n;                        // 64n f32 region; holds bf16 hs
    float* bufA    = bufH + (size_t)n * NF;           // 64n f32 region (hs2)
    int*   counts  = (int*)(bufA + (size_t)n * NF);   // n
    int*   row_ptr = counts + n;                      // n
    int*   col     = row_ptr + n;                     // E
    int*   hmat    = col + E;                         // NB*NBLK
    int*   bptr    = hmat + ntot;                     // NB+1
    int*   bsums   = bptr + NB + 1;                   // <=2048
    int*   pairs   = (int*)bufH;                      // E (build lifetime only)
    ushort_t* hsb  = (ushort_t*)bufH;                 // 64n bf16 layer-1 hs
    ushort_t* hs2b = (ushort_t*)bufA;                 // 64n bf16 layer-2 hs

    // ---- bucket sort by dst (contention-free, full-line write segments) ----
    k_histA<<<NBLK, 256, 0, stream>>>(dst, hmat, E, NB, chunk);
    k_scan_a<<<nsb, 256, 0, stream>>>(hmat, hmat, bsums, ntot);
    k_scan_addb<<<(ntot + 255) / 256, 256, 0, stream>>>(hmat, bsums, bptr, ntot, E);
    k_placeB<<<NBLK, 256, 0, stream>>>(src, dst, hmat, pairs, E, NB, chunk);

    // ---- fused node-level CSR + dinv (one block per 256-node bucket) ----
    k_csr<<<NB, 256, 0, stream>>>(bptr, pairs, row_ptr, counts, dinv, col, n);

    // ---- layer 1 (MFMA): hs = bf16((x @ W1) * dinv) ----
    k_mm1<<<(ntiles + 3) / 4, 256, 0, stream>>>(x, W1, dinv, hsb, n);

    // ---- fused pull1 (+b1, relu) + GEMM2 (MFMA): hs2 = bf16((act @ W2) * dinv) ----
    k_pullmm<<<(n + 15) / 16, 256, 0, stream>>>(hsb, dinv, row_ptr, counts, col, b1,
                                                W2, hs2b, n);

    // ---- pull2 (+b2, relu) + fused decode ----
    k_pull2<<<(n + 15) / 16, 256, 0, stream>>>(hs2b, dinv, row_ptr, counts, col, b2,
                                               Wd, bd, out, n);
}

// Round 22
// 133.723 us; speedup vs baseline: 2.1124x; 1.0020x over previous
//
#include <hip/hip_runtime.h>

#define NF 64      // hidden width (both layers)
#define NBLK 256   // chunks for the two-pass bucket sort
#define SH 8       // bucket = dst >> SH  (256 nodes per bucket)
#define BMSK 255
#define MAXNB 2048 // LDS histogram capacity (NB = ceil(n/256) <= 2048 -> n <= 524288)

typedef unsigned short ushort_t;
typedef __attribute__((ext_vector_type(8))) short short8;   // 8 bf16 = 4 VGPR (MFMA A/B frag)
typedef __attribute__((ext_vector_type(4))) float f32x4;    // MFMA C/D frag

__device__ inline ushort_t f2bf(float f) {               // RNE f32 -> bf16
    unsigned u = __float_as_uint(f);
    return (ushort_t)((u + 0x7fffu + ((u >> 16) & 1u)) >> 16);
}
__device__ inline float bfhi(unsigned x) { return __uint_as_float(x & 0xffff0000u); }
__device__ inline float bflo(unsigned x) { return __uint_as_float(x << 16); }

#define PACK8(b, ua, ub) \
    b[0] = (short)f2bf(ua.x); b[1] = (short)f2bf(ua.y); \
    b[2] = (short)f2bf(ua.z); b[3] = (short)f2bf(ua.w); \
    b[4] = (short)f2bf(ub.x); b[5] = (short)f2bf(ub.y); \
    b[6] = (short)f2bf(ub.z); b[7] = (short)f2bf(ub.w);

// =================== scan utilities ===================

__device__ inline int wave_incl_scan(int x, int lane) {
#pragma unroll
    for (int o = 1; o < 64; o <<= 1) { int y = __shfl_up(x, o, 64); if (lane >= o) x += y; }
    return x;
}

// 1024 elements per block (256 threads x 4); in-place safe
__global__ __launch_bounds__(256) void k_scan_a(const int* __restrict__ in, int* __restrict__ out,
                                                int* __restrict__ bsums, int n) {
    int t = threadIdx.x, lane = t & 63, wv = t >> 6;
    int base = blockIdx.x * 1024 + t * 4;
    int v[4]; int s = 0;
#pragma unroll
    for (int k = 0; k < 4; ++k) { int i = base + k; int x = (i < n) ? in[i] : 0; v[k] = s; s += x; }
    int incl = wave_incl_scan(s, lane);
    __shared__ int ws[4];
    if (lane == 63) ws[wv] = incl;
    __syncthreads();
    int wofs = 0;
#pragma unroll
    for (int w = 0; w < 4; ++w) if (w < wv) wofs += ws[w];
    int texcl = wofs + incl - s;
#pragma unroll
    for (int k = 0; k < 4; ++k) { int i = base + k; if (i < n) out[i] = texcl + v[k]; }
    if (t == 255) bsums[blockIdx.x] = wofs + incl;
}

// add block sums (prefix computed locally from raw bsums: <=2048 entries, one wave);
// also emit bucket pointers (bptr[b] = scanned hmat[b*NBLK], bptr[NB] = E)
__global__ __launch_bounds__(256) void k_scan_addb(int* __restrict__ data, const int* __restrict__ bsums,
                                                   int* __restrict__ bptr, int ntot, int E) {
    __shared__ int off_s;
    int t = threadIdx.x;
    int myChunk = (int)(blockIdx.x >> 2);          // this block's 1024-chunk index
    if (t < 64) {
        int s = 0;
        for (int i = t; i < myChunk; i += 64) s += bsums[i];
#pragma unroll
        for (int o = 32; o > 0; o >>= 1) s += __shfl_xor(s, o, 64);
        if (t == 0) off_s = s;
    }
    __syncthreads();
    int off = off_s;
    int i = blockIdx.x * 256 + t;
    if (i < ntot) {
        int v = data[i] + off;
        data[i] = v;
        if ((i & (NBLK - 1)) == 0) bptr[i / NBLK] = v;
    }
    if (i == 0) bptr[ntot / NBLK] = E;
}

// =================== contention-free bucket sort (bucket = dst >> SH, 256 nodes/bucket) ===================

__global__ __launch_bounds__(256) void k_histA(const int* __restrict__ dst, int* __restrict__ hmat,
                                               int E, int NB, int chunk) {
    __shared__ int h[MAXNB];
    int blk = blockIdx.x;
    for (int i = threadIdx.x; i < NB; i += 256) h[i] = 0;
    __syncthreads();
    int beg = blk * chunk, end = beg + chunk; if (end > E) end = E;
    for (int e = beg + threadIdx.x; e < end; e += 256) atomicAdd(&h[dst[e] >> SH], 1);
    __syncthreads();
    for (int i = threadIdx.x; i < NB; i += 256) hmat[i * NBLK + blk] = h[i];
}

__global__ __launch_bounds__(256) void k_placeB(const int* __restrict__ src, const int* __restrict__ dst,
                                                const int* __restrict__ hmat, int* __restrict__ pairs,
                                                int E, int NB, int chunk) {
    __shared__ int cur[MAXNB];
    int blk = blockIdx.x;
    for (int i = threadIdx.x; i < NB; i += 256) cur[i] = hmat[i * NBLK + blk];
    __syncthreads();
    int beg = blk * chunk, end = beg + chunk; if (end > E) end = E;
    for (int e = beg + threadIdx.x; e < end; e += 256) {
        int s = src[e], d = dst[e];
        int off = atomicAdd(&cur[d >> SH], 1);
        pairs[off] = (s << SH) | (d & BMSK);
    }
}

// =================== fused node-level CSR: hist + 256-scan + row_ptr/cnt/dinv + place ===================
// one block per 256-node bucket
__global__ __launch_bounds__(256) void k_csr(const int* __restrict__ bptr, const int* __restrict__ pairs,
                                             int* __restrict__ row_ptr, int* __restrict__ cnt,
                                             float* __restrict__ dinv, int* __restrict__ col, int n) {
    __shared__ int h[256];
    __shared__ int cur[256];
    __shared__ int ws[4];
    int b = blockIdx.x, t = threadIdx.x;
    h[t] = 0;
    __syncthreads();
    int beg = bptr[b], end = bptr[b + 1];
    for (int j = beg + t; j < end; j += 256) atomicAdd(&h[pairs[j] & BMSK], 1);
    __syncthreads();
    int c = h[t];
    int incl = wave_incl_scan(c, t & 63);
    if ((t & 63) == 63) ws[t >> 6] = incl;
    __syncthreads();
    int wofs = 0;
#pragma unroll
    for (int w = 0; w < 4; ++w) if (w < (t >> 6)) wofs += ws[w];
    int ex = wofs + incl - c;
    int node = (b << SH) + t;
    if (node < n) {
        row_ptr[node] = beg + ex;
        cnt[node] = c;
        dinv[node] = rsqrtf(1.0f + (float)c);
    }
    cur[t] = beg + ex;
    __syncthreads();
    for (int j = beg + t; j < end; j += 256) {
        int pk = pairs[j];
        int p = atomicAdd(&cur[pk & BMSK], 1);
        col[p] = pk >> SH;
    }
}

// =================== GEMM1 via MFMA (f32 -> bf16 in-register, K=128) — round-16 validated ===================
__global__ __launch_bounds__(256) void k_mm1(
    const float* __restrict__ X, const float* __restrict__ W,
    const float* __restrict__ dinv, ushort_t* __restrict__ out, int n)
{
    __shared__ ushort_t wf[16 * 512];            // 16 KB: 16 frags x (64 lanes x 8 bf16)
    int t = threadIdx.x;
    for (int idx = t; idx < 128 * 64; idx += 256) {
        int k = idx >> 6, c = idx & 63;
        int f = ((k >> 5) << 2) | (c >> 4);
        int ln = (c & 15) | (((k >> 3) & 3) << 4);
        wf[f * 512 + ln * 8 + (k & 7)] = f2bf(W[idx]);
    }
    __syncthreads();

    int lane = t & 63, wv = t >> 6;
    int r16 = lane & 15, kg = lane >> 4;
    int tile = blockIdx.x * 4 + wv;              // one 16-row tile per wave
    int row = tile * 16 + r16;
    int r = (row < n) ? row : (n - 1);           // clamp: dup loads, stores guarded
    const float* pX = X + (size_t)r * 128 + kg * 8;

    // prefetch all 8 x-chunks (4 k-slices x 32 B) for MLP
    float4 u0a = *(const float4*)(pX + 0),   u0b = *(const float4*)(pX + 4);
    float4 u1a = *(const float4*)(pX + 32),  u1b = *(const float4*)(pX + 36);
    float4 u2a = *(const float4*)(pX + 64),  u2b = *(const float4*)(pX + 68);
    float4 u3a = *(const float4*)(pX + 96),  u3b = *(const float4*)(pX + 100);

    short8 b0, b1, b2, b3;
    PACK8(b0, u0a, u0b); PACK8(b1, u1a, u1b);
    PACK8(b2, u2a, u2b); PACK8(b3, u3a, u3b);

    short8 a0[4], a1[4], a2[4], a3[4];
#pragma unroll
    for (int f = 0; f < 4; ++f) {
        a0[f] = *(const short8*)(wf + (0 + f) * 512 + lane * 8);
        a1[f] = *(const short8*)(wf + (4 + f) * 512 + lane * 8);
        a2[f] = *(const short8*)(wf + (8 + f) * 512 + lane * 8);
        a3[f] = *(const short8*)(wf + (12 + f) * 512 + lane * 8);
    }

    f32x4 z = {0.f, 0.f, 0.f, 0.f};
    f32x4 acc[4];
#pragma unroll
    for (int f = 0; f < 4; ++f)
        acc[f] = __builtin_amdgcn_mfma_f32_16x16x32_bf16(a0[f], b0, z, 0, 0, 0);
#pragma unroll
    for (int f = 0; f < 4; ++f)
        acc[f] = __builtin_amdgcn_mfma_f32_16x16x32_bf16(a1[f], b1, acc[f], 0, 0, 0);
#pragma unroll
    for (int f = 0; f < 4; ++f)
        acc[f] = __builtin_amdgcn_mfma_f32_16x16x32_bf16(a2[f], b2, acc[f], 0, 0, 0);
#pragma unroll
    for (int f = 0; f < 4; ++f)
        acc[f] = __builtin_amdgcn_mfma_f32_16x16x32_bf16(a3[f], b3, acc[f], 0, 0, 0);

    if (row < n) {
        float di = dinv[row];
#pragma unroll
        for (int f = 0; f < 4; ++f) {
            ushort4 o;
            o.x = f2bf(acc[f][0] * di); o.y = f2bf(acc[f][1] * di);
            o.z = f2bf(acc[f][2] * di); o.w = f2bf(acc[f][3] * di);
            *(ushort4*)(out + (size_t)row * NF + f * 16 + kg * 4) = o;
        }
    }
}

// =================== fused pull1 + GEMM2 ===================
// Block = 256 threads = 16 dst nodes = one 16-row MFMA tile.
// Phase A (pull): act_row(d) = relu(dinv[d]*(hs[d]+sum hs[src])+b1), written directly in
//   B-FRAGMENT ORDER to LDS (bfrag[ks][kg<<4|r16][8]) -> phase-B reads are bank-conflict-free.
//   Frag coords from feature chunk lt: ks=lt>>3, kg=(lt>>1)&3, half=lt&1  (f = lt*4+j ==
//   kg*8 + ks*32 + half*4 + j, matching the round-15-validated B mapping).
// Phase B (mm2): hs2[d] = bf16((act @ W2) * dinv[d]); wave wv -> columns [wv*16, wv*16+16).
// Gathers use uniform-base + 32-bit byte offsets (n*128B < 4GB) to cut address VALU.
__global__ __launch_bounds__(256) void k_pullmm(
    const ushort_t* __restrict__ hs, const float* __restrict__ dinv,
    const int* __restrict__ row_ptr, const int* __restrict__ cnt,
    const int* __restrict__ col, const float* __restrict__ bias,
    const float* __restrict__ W, ushort_t* __restrict__ out, int n)
{
    __shared__ ushort_t wf[8 * 512];             // W2 frags (8 KB), k_mm2 swizzle
    __shared__ ushort_t bfrag[1024];             // act tile in B-frag order (2 KB)
    int t = threadIdx.x;
    for (int idx = t; idx < 64 * 64; idx += 256) {
        int k = idx >> 6, c = idx & 63;
        int f = ((k >> 5) << 2) | (c >> 4);
        int ln = (c & 15) | (((k >> 3) & 3) << 4);
        wf[f * 512 + ln * 8 + (k & 7)] = f2bf(W[idx]);
    }

    // ---- phase A: pull (one 16-lane group per node) ----
    int d = blockIdx.x * 16 + (t >> 4);
    int lt = t & 15;
    int fo = lt << 2;
    int grpbase = t & 48;
    const char* __restrict__ hp = (const char*)hs;
    unsigned lt8 = (unsigned)lt << 3;
    float rx = 0.f, ry = 0.f, rz = 0.f, rw = 0.f;
    if (d < n) {
        uint2 sv = *(const uint2*)(hp + (((unsigned)d << 7) + lt8));
        float4 acc = make_float4(bflo(sv.x), bfhi(sv.x), bflo(sv.y), bfhi(sv.y));
        int beg = row_ptr[d], deg = cnt[d];
        for (int jb = 0; jb < deg; jb += 16) {
            int m = deg - jb; if (m > 16) m = 16;
            int idx = (lt < m) ? col[beg + jb + lt] : 0;
            uint2 v[16];
#pragma unroll
            for (int u = 0; u < 16; ++u) {
                int kk = (u < m) ? u : (m - 1);              // clamp: dup loads hit L1
                int s = __shfl(idx, grpbase + kk, 64);
                v[u] = *(const uint2*)(hp + (((unsigned)s << 7) + lt8));
            }
#pragma unroll
            for (int u = 0; u < 16; ++u) {
                if (u < m) {
                    acc.x += bflo(v[u].x); acc.y += bfhi(v[u].x);
                    acc.z += bflo(v[u].y); acc.w += bfhi(v[u].y);
                }
            }
        }
        float di = dinv[d];
        float4 bv = *(const float4*)(bias + fo);
        rx = fmaxf(fmaf(acc.x, di, bv.x), 0.0f);
        ry = fmaxf(fmaf(acc.y, di, bv.y), 0.0f);
        rz = fmaxf(fmaf(acc.z, di, bv.z), 0.0f);
        rw = fmaxf(fmaf(acc.w, di, bv.w), 0.0f);
    }
    {
        ushort4 o;
        o.x = f2bf(rx); o.y = f2bf(ry); o.z = f2bf(rz); o.w = f2bf(rw);
        int g = t >> 4;
        int ks = lt >> 3, kg2 = (lt >> 1) & 3, half = lt & 1;
        *(ushort4*)(bfrag + ks * 512 + (((kg2 << 4) | g) << 3) + (half << 2)) = o;
    }
    __syncthreads();

    // ---- phase B: MFMA (wave wv -> columns [wv*16, wv*16+16)) ----
    int lane = t & 63, wv = t >> 6;
    int r16 = lane & 15, kg = lane >> 4;
    short8 aflo = *(const short8*)(wf + wv * 512 + lane * 8);
    short8 afhi = *(const short8*)(wf + (4 + wv) * 512 + lane * 8);
    short8 bb0 = *(const short8*)(bfrag + lane * 8);         // ks=0, conflict-free
    short8 bb1 = *(const short8*)(bfrag + 512 + lane * 8);   // ks=1

    f32x4 z = {0.f, 0.f, 0.f, 0.f};
    f32x4 acc2 = __builtin_amdgcn_mfma_f32_16x16x32_bf16(aflo, bb0, z, 0, 0, 0);
    acc2 = __builtin_amdgcn_mfma_f32_16x16x32_bf16(afhi, bb1, acc2, 0, 0, 0);

    int row = blockIdx.x * 16 + r16;
    if (row < n) {
        float di = dinv[row];
        ushort4 o;
        o.x = f2bf(acc2[0] * di); o.y = f2bf(acc2[1] * di);
        o.z = f2bf(acc2[2] * di); o.w = f2bf(acc2[3] * di);
        *(ushort4*)((char*)out + (((unsigned)row << 7) + ((unsigned)wv << 5) + ((unsigned)kg << 3))) = o;
    }
}

// =================== pull2 + fused decode: out[d] = relu(dinv*(...)+b2) . Wd + bd ===================
__global__ __launch_bounds__(256) void k_pull2(
    const ushort_t* __restrict__ hs, const float* __restrict__ dinv,
    const int* __restrict__ row_ptr, const int* __restrict__ cnt,
    const int* __restrict__ col, const float* __restrict__ bias,
    const float* __restrict__ Wd, const float* __restrict__ bd,
    float* __restrict__ outv, int n)
{
    int d = blockIdx.x * 16 + (threadIdx.x >> 4);
    if (d >= n) return;
    int lt = threadIdx.x & 15;            // lane in group
    int fo = lt << 2;                     // feature offset (4 features/lane)
    int grpbase = threadIdx.x & 48;       // group base lane within wave
    const char* __restrict__ hp = (const char*)hs;
    unsigned lt8 = (unsigned)lt << 3;
    int beg = row_ptr[d], deg = cnt[d];

    // self-loop (bf16 row, 8B/lane)
    uint2 sv = *(const uint2*)(hp + (((unsigned)d << 7) + lt8));
    float4 acc = make_float4(bflo(sv.x), bfhi(sv.x), bflo(sv.y), bfhi(sv.y));

    for (int jb = 0; jb < deg; jb += 16) {
        int m = deg - jb; if (m > 16) m = 16;
        int idx = (lt < m) ? col[beg + jb + lt] : 0;
        uint2 v[16];
#pragma unroll
        for (int u = 0; u < 16; ++u) {
            int kk = (u < m) ? u : (m - 1);                  // clamp: dup loads hit L1
            int s = __shfl(idx, grpbase + kk, 64);
            v[u] = *(const uint2*)(hp + (((unsigned)s << 7) + lt8));
        }
#pragma unroll
        for (int u = 0; u < 16; ++u) {
            if (u < m) {
                acc.x += bflo(v[u].x); acc.y += bfhi(v[u].x);
                acc.z += bflo(v[u].y); acc.w += bfhi(v[u].y);
            }
        }
    }

    float di = dinv[d];
    float4 bv = *(const float4*)(bias + fo);
    float rx = fmaxf(fmaf(acc.x, di, bv.x), 0.0f);
    float ry = fmaxf(fmaf(acc.y, di, bv.y), 0.0f);
    float rz = fmaxf(fmaf(acc.z, di, bv.z), 0.0f);
    float rw = fmaxf(fmaf(acc.w, di, bv.w), 0.0f);

    float4 wv = *(const float4*)(Wd + fo);
    float vsum = rx * wv.x + ry * wv.y + rz * wv.z + rw * wv.w;
#pragma unroll
    for (int o = 1; o < 16; o <<= 1) vsum += __shfl_xor(vsum, o, 64);
    if (lt == 0) outv[d] = vsum + bd[0];
}

extern "C" void kernel_launch(void* const* d_in, const int* in_sizes, int n_in,
                              void* d_out, int out_size, void* d_ws, size_t ws_size,
                              hipStream_t stream) {
    const float* x  = (const float*)d_in[0];
    const int*   ei = (const int*)d_in[1];
    const float* W1 = (const float*)d_in[2];
    const float* b1 = (const float*)d_in[3];
    const float* W2 = (const float*)d_in[4];
    const float* b2 = (const float*)d_in[5];
    const float* Wd = (const float*)d_in[6];
    const float* bd = (const float*)d_in[7];
    float* out = (float*)d_out;

    int n = in_sizes[0] / 128;
    int E = in_sizes[1] / 2;
    const int* src = ei;
    const int* dst = ei + E;

    int NB = (n + (1 << SH) - 1) >> SH;     // dst buckets of 256 nodes (~391)
    int chunk = (E + NBLK - 1) / NBLK;
    int ntot = NB * NBLK;                   // hist matrix size (~100k)
    int nsb = (ntot + 1023) / 1024;         // scan blocks over hmat (<= 2048)
    int ntiles = (n + 15) / 16;             // 16-row MFMA tiles

    // workspace layout (4-byte elems) — pairs aliases bufH region (build ends before gemm1)
    float* dinv    = (float*)d_ws;                    // n
    float* bufH    = dinv + n;                        // 64n f32 region; holds bf16 hs
    float* bufA    = bufH + (size_t)n * NF;           // 64n f32 region (hs2)
    int*   counts  = (int*)(bufA + (size_t)n * NF);   // n
    int*   row_ptr = counts + n;                      // n
    int*   col     = row_ptr + n;                     // E
    int*   hmat    = col + E;                         // NB*NBLK
    int*   bptr    = hmat + ntot;                     // NB+1
    int*   bsums   = bptr + NB + 1;                   // <=2048
    int*   pairs   = (int*)bufH;                      // E (build lifetime only)
    ushort_t* hsb  = (ushort_t*)bufH;                 // 64n bf16 layer-1 hs
    ushort_t* hs2b = (ushort_t*)bufA;                 // 64n bf16 layer-2 hs

    // ---- bucket sort by dst (contention-free, full-line write segments) ----
    k_histA<<<NBLK, 256, 0, stream>>>(dst, hmat, E, NB, chunk);
    k_scan_a<<<nsb, 256, 0, stream>>>(hmat, hmat, bsums, ntot);
    k_scan_addb<<<(ntot + 255) / 256, 256, 0, stream>>>(hmat, bsums, bptr, ntot, E);
    k_placeB<<<NBLK, 256, 0, stream>>>(src, dst, hmat, pairs, E, NB, chunk);

    // ---- fused node-level CSR + dinv (one block per 256-node bucket) ----
    k_csr<<<NB, 256, 0, stream>>>(bptr, pairs, row_ptr, counts, dinv, col, n);

    // ---- layer 1 (MFMA): hs = bf16((x @ W1) * dinv) ----
    k_mm1<<<(ntiles + 3) / 4, 256, 0, stream>>>(x, W1, dinv, hsb, n);

    // ---- fused pull1 (+b1, relu) + GEMM2 (MFMA): hs2 = bf16((act @ W2) * dinv) ----
    k_pullmm<<<(n + 15) / 16, 256, 0, stream>>>(hsb, dinv, row_ptr, counts, col, b1,
                                                W2, hs2b, n);

    // ---- pull2 (+b2, relu) + fused decode ----
    k_pull2<<<(n + 15) / 16, 256, 0, stream>>>(hs2b, dinv, row_ptr, counts, col, b2,
                                               Wd, bd, out, n);
}

// Round 23
// 126.557 us; speedup vs baseline: 2.2320x; 1.0566x over previous
//
#include <hip/hip_runtime.h>

#define NF 64      // hidden width (both layers)
#define NBLK 256   // chunks for the two-pass bucket sort
#define SH 8       // bucket = dst >> SH  (256 nodes per bucket)
#define BMSK 255
#define MAXNB 2048 // LDS histogram capacity (NB = ceil(n/256) <= 2048 -> n <= 524288)

typedef unsigned short ushort_t;
typedef __attribute__((ext_vector_type(8))) short short8;   // 8 bf16 = 4 VGPR (MFMA A/B frag)
typedef __attribute__((ext_vector_type(4))) float f32x4;    // MFMA C/D frag

__device__ inline ushort_t f2bf(float f) {               // RNE f32 -> bf16
    unsigned u = __float_as_uint(f);
    return (ushort_t)((u + 0x7fffu + ((u >> 16) & 1u)) >> 16);
}
__device__ inline float bfhi(unsigned x) { return __uint_as_float(x & 0xffff0000u); }
__device__ inline float bflo(unsigned x) { return __uint_as_float(x << 16); }

#define PACK8(b, ua, ub) \
    b[0] = (short)f2bf(ua.x); b[1] = (short)f2bf(ua.y); \
    b[2] = (short)f2bf(ua.z); b[3] = (short)f2bf(ua.w); \
    b[4] = (short)f2bf(ub.x); b[5] = (short)f2bf(ub.y); \
    b[6] = (short)f2bf(ub.z); b[7] = (short)f2bf(ub.w);

// =================== scan utilities ===================

__device__ inline int wave_incl_scan(int x, int lane) {
#pragma unroll
    for (int o = 1; o < 64; o <<= 1) { int y = __shfl_up(x, o, 64); if (lane >= o) x += y; }
    return x;
}

// 1024 elements per block (256 threads x 4); in-place safe
__global__ __launch_bounds__(256) void k_scan_a(const int* __restrict__ in, int* __restrict__ out,
                                                int* __restrict__ bsums, int n) {
    int t = threadIdx.x, lane = t & 63, wv = t >> 6;
    int base = blockIdx.x * 1024 + t * 4;
    int v[4]; int s = 0;
#pragma unroll
    for (int k = 0; k < 4; ++k) { int i = base + k; int x = (i < n) ? in[i] : 0; v[k] = s; s += x; }
    int incl = wave_incl_scan(s, lane);
    __shared__ int ws[4];
    if (lane == 63) ws[wv] = incl;
    __syncthreads();
    int wofs = 0;
#pragma unroll
    for (int w = 0; w < 4; ++w) if (w < wv) wofs += ws[w];
    int texcl = wofs + incl - s;
#pragma unroll
    for (int k = 0; k < 4; ++k) { int i = base + k; if (i < n) out[i] = texcl + v[k]; }
    if (t == 255) bsums[blockIdx.x] = wofs + incl;
}

// add block sums (prefix computed locally from raw bsums: <=2048 entries, one wave);
// also emit bucket pointers (bptr[b] = scanned hmat[b*NBLK], bptr[NB] = E)
__global__ __launch_bounds__(256) void k_scan_addb(int* __restrict__ data, const int* __restrict__ bsums,
                                                   int* __restrict__ bptr, int ntot, int E) {
    __shared__ int off_s;
    int t = threadIdx.x;
    int myChunk = (int)(blockIdx.x >> 2);          // this block's 1024-chunk index
    if (t < 64) {
        int s = 0;
        for (int i = t; i < myChunk; i += 64) s += bsums[i];
#pragma unroll
        for (int o = 32; o > 0; o >>= 1) s += __shfl_xor(s, o, 64);
        if (t == 0) off_s = s;
    }
    __syncthreads();
    int off = off_s;
    int i = blockIdx.x * 256 + t;
    if (i < ntot) {
        int v = data[i] + off;
        data[i] = v;
        if ((i & (NBLK - 1)) == 0) bptr[i / NBLK] = v;
    }
    if (i == 0) bptr[ntot / NBLK] = E;
}

// =================== contention-free bucket sort (bucket = dst >> SH, 256 nodes/bucket) ===================
// prologue: pre-swizzle W1/W2 into bf16 MFMA-fragment order in global ws (once, not per GEMM block)

__global__ __launch_bounds__(256) void k_histA(const int* __restrict__ dst, int* __restrict__ hmat,
                                               int E, int NB, int chunk,
                                               const float* __restrict__ W1, const float* __restrict__ W2,
                                               ushort_t* __restrict__ w1f, ushort_t* __restrict__ w2f) {
    __shared__ int h[MAXNB];
    int blk = blockIdx.x;
    // ---- W pre-swizzle (12288 elems over 65536 threads) ----
    int gid = blk * 256 + threadIdx.x;
    if (gid < 8192) {                                     // W1: [128][64]
        int k = gid >> 6, c = gid & 63;
        int f = ((k >> 5) << 2) | (c >> 4);
        int ln = (c & 15) | (((k >> 3) & 3) << 4);
        w1f[f * 512 + ln * 8 + (k & 7)] = f2bf(W1[gid]);
    } else if (gid < 12288) {                             // W2: [64][64]
        int i2 = gid - 8192;
        int k = i2 >> 6, c = i2 & 63;
        int f = ((k >> 5) << 2) | (c >> 4);
        int ln = (c & 15) | (((k >> 3) & 3) << 4);
        w2f[f * 512 + ln * 8 + (k & 7)] = f2bf(W2[i2]);
    }

    for (int i = threadIdx.x; i < NB; i += 256) h[i] = 0;
    __syncthreads();
    int beg = blk * chunk, end = beg + chunk; if (end > E) end = E;
    for (int e = beg + threadIdx.x; e < end; e += 256) atomicAdd(&h[dst[e] >> SH], 1);
    __syncthreads();
    for (int i = threadIdx.x; i < NB; i += 256) hmat[i * NBLK + blk] = h[i];
}

__global__ __launch_bounds__(256) void k_placeB(const int* __restrict__ src, const int* __restrict__ dst,
                                                const int* __restrict__ hmat, int* __restrict__ pairs,
                                                int E, int NB, int chunk) {
    __shared__ int cur[MAXNB];
    int blk = blockIdx.x;
    for (int i = threadIdx.x; i < NB; i += 256) cur[i] = hmat[i * NBLK + blk];
    __syncthreads();
    int beg = blk * chunk, end = beg + chunk; if (end > E) end = E;
    for (int e = beg + threadIdx.x; e < end; e += 256) {
        int s = src[e], d = dst[e];
        int off = atomicAdd(&cur[d >> SH], 1);
        pairs[off] = (s << SH) | (d & BMSK);
    }
}

// =================== fused node-level CSR: hist + 256-scan + row_ptr/cnt/dinv + place ===================
// one block per 256-node bucket
__global__ __launch_bounds__(256) void k_csr(const int* __restrict__ bptr, const int* __restrict__ pairs,
                                             int* __restrict__ row_ptr, int* __restrict__ cnt,
                                             float* __restrict__ dinv, int* __restrict__ col, int n) {
    __shared__ int h[256];
    __shared__ int cur[256];
    __shared__ int ws[4];
    int b = blockIdx.x, t = threadIdx.x;
    h[t] = 0;
    __syncthreads();
    int beg = bptr[b], end = bptr[b + 1];
    for (int j = beg + t; j < end; j += 256) atomicAdd(&h[pairs[j] & BMSK], 1);
    __syncthreads();
    int c = h[t];
    int incl = wave_incl_scan(c, t & 63);
    if ((t & 63) == 63) ws[t >> 6] = incl;
    __syncthreads();
    int wofs = 0;
#pragma unroll
    for (int w = 0; w < 4; ++w) if (w < (t >> 6)) wofs += ws[w];
    int ex = wofs + incl - c;
    int node = (b << SH) + t;
    if (node < n) {
        row_ptr[node] = beg + ex;
        cnt[node] = c;
        dinv[node] = rsqrtf(1.0f + (float)c);
    }
    cur[t] = beg + ex;
    __syncthreads();
    for (int j = beg + t; j < end; j += 256) {
        int pk = pairs[j];
        int p = atomicAdd(&cur[pk & BMSK], 1);
        col[p] = pk >> SH;
    }
}

// =================== GEMM1 via MFMA (f32 -> bf16 in-register, K=128) ===================
// A-frags loaded straight from pre-swizzled global w1f (24 KB L2-resident) — no LDS staging.
__global__ __launch_bounds__(256) void k_mm1(
    const float* __restrict__ X, const ushort_t* __restrict__ w1f,
    const float* __restrict__ dinv, ushort_t* __restrict__ out, int n)
{
    int t = threadIdx.x;
    int lane = t & 63, wv = t >> 6;
    int r16 = lane & 15, kg = lane >> 4;

    short8 a0[4], a1[4], a2[4], a3[4];
#pragma unroll
    for (int f = 0; f < 4; ++f) {
        a0[f] = *(const short8*)(w1f + (0 + f) * 512 + lane * 8);
        a1[f] = *(const short8*)(w1f + (4 + f) * 512 + lane * 8);
        a2[f] = *(const short8*)(w1f + (8 + f) * 512 + lane * 8);
        a3[f] = *(const short8*)(w1f + (12 + f) * 512 + lane * 8);
    }

    int tile = blockIdx.x * 4 + wv;              // one 16-row tile per wave
    int row = tile * 16 + r16;
    int r = (row < n) ? row : (n - 1);           // clamp: dup loads, stores guarded
    const float* pX = X + (size_t)r * 128 + kg * 8;

    // prefetch all 8 x-chunks (4 k-slices x 32 B) for MLP
    float4 u0a = *(const float4*)(pX + 0),   u0b = *(const float4*)(pX + 4);
    float4 u1a = *(const float4*)(pX + 32),  u1b = *(const float4*)(pX + 36);
    float4 u2a = *(const float4*)(pX + 64),  u2b = *(const float4*)(pX + 68);
    float4 u3a = *(const float4*)(pX + 96),  u3b = *(const float4*)(pX + 100);

    short8 b0, b1, b2, b3;
    PACK8(b0, u0a, u0b); PACK8(b1, u1a, u1b);
    PACK8(b2, u2a, u2b); PACK8(b3, u3a, u3b);

    f32x4 z = {0.f, 0.f, 0.f, 0.f};
    f32x4 acc[4];
#pragma unroll
    for (int f = 0; f < 4; ++f)
        acc[f] = __builtin_amdgcn_mfma_f32_16x16x32_bf16(a0[f], b0, z, 0, 0, 0);
#pragma unroll
    for (int f = 0; f < 4; ++f)
        acc[f] = __builtin_amdgcn_mfma_f32_16x16x32_bf16(a1[f], b1, acc[f], 0, 0, 0);
#pragma unroll
    for (int f = 0; f < 4; ++f)
        acc[f] = __builtin_amdgcn_mfma_f32_16x16x32_bf16(a2[f], b2, acc[f], 0, 0, 0);
#pragma unroll
    for (int f = 0; f < 4; ++f)
        acc[f] = __builtin_amdgcn_mfma_f32_16x16x32_bf16(a3[f], b3, acc[f], 0, 0, 0);

    if (row < n) {
        float di = dinv[row];
#pragma unroll
        for (int f = 0; f < 4; ++f) {
            ushort4 o;
            o.x = f2bf(acc[f][0] * di); o.y = f2bf(acc[f][1] * di);
            o.z = f2bf(acc[f][2] * di); o.w = f2bf(acc[f][3] * di);
            *(ushort4*)(out + (size_t)row * NF + f * 16 + kg * 4) = o;
        }
    }
}

// =================== fused pull1 + GEMM2 ===================
// Block = 256 threads = 16 dst nodes = one 16-row MFMA tile.
// Phase A (pull): act_row(d) = relu(dinv[d]*(hs[d]+sum hs[src])+b1), written in B-frag order
//   to LDS bfrag (2 KB). Phase B: A-frags from pre-swizzled global w2f (prefetched before
//   the gather loop); wave wv computes column slab [wv*16, wv*16+16).
__global__ __launch_bounds__(256) void k_pullmm(
    const ushort_t* __restrict__ hs, const float* __restrict__ dinv,
    const int* __restrict__ row_ptr, const int* __restrict__ cnt,
    const int* __restrict__ col, const float* __restrict__ bias,
    const ushort_t* __restrict__ w2f, ushort_t* __restrict__ out, int n)
{
    __shared__ ushort_t bfrag[1024];             // act tile in B-frag order (2 KB)
    int t = threadIdx.x;
    int lane = t & 63, wv = t >> 6;

    // prefetch A-frags (L2-resident; latency hides under the gather loop)
    short8 aflo = *(const short8*)(w2f + wv * 512 + lane * 8);
    short8 afhi = *(const short8*)(w2f + (4 + wv) * 512 + lane * 8);

    // ---- phase A: pull (one 16-lane group per node) ----
    int d = blockIdx.x * 16 + (t >> 4);
    int lt = t & 15;
    int fo = lt << 2;
    int grpbase = t & 48;
    const char* __restrict__ hp = (const char*)hs;
    unsigned lt8 = (unsigned)lt << 3;
    float rx = 0.f, ry = 0.f, rz = 0.f, rw = 0.f;
    if (d < n) {
        uint2 sv = *(const uint2*)(hp + (((unsigned)d << 7) + lt8));
        float4 acc = make_float4(bflo(sv.x), bfhi(sv.x), bflo(sv.y), bfhi(sv.y));
        int beg = row_ptr[d], deg = cnt[d];
        for (int jb = 0; jb < deg; jb += 16) {
            int m = deg - jb; if (m > 16) m = 16;
            int idx = (lt < m) ? col[beg + jb + lt] : 0;
            uint2 v[16];
#pragma unroll
            for (int u = 0; u < 16; ++u) {
                int kk = (u < m) ? u : (m - 1);              // clamp: dup loads hit L1
                int s = __shfl(idx, grpbase + kk, 64);
                v[u] = *(const uint2*)(hp + (((unsigned)s << 7) + lt8));
            }
#pragma unroll
            for (int u = 0; u < 16; ++u) {
                if (u < m) {
                    acc.x += bflo(v[u].x); acc.y += bfhi(v[u].x);
                    acc.z += bflo(v[u].y); acc.w += bfhi(v[u].y);
                }
            }
        }
        float di = dinv[d];
        float4 bv = *(const float4*)(bias + fo);
        rx = fmaxf(fmaf(acc.x, di, bv.x), 0.0f);
        ry = fmaxf(fmaf(acc.y, di, bv.y), 0.0f);
        rz = fmaxf(fmaf(acc.z, di, bv.z), 0.0f);
        rw = fmaxf(fmaf(acc.w, di, bv.w), 0.0f);
    }
    {
        ushort4 o;
        o.x = f2bf(rx); o.y = f2bf(ry); o.z = f2bf(rz); o.w = f2bf(rw);
        int g = t >> 4;
        int ks = lt >> 3, kg2 = (lt >> 1) & 3, half = lt & 1;
        *(ushort4*)(bfrag + ks * 512 + (((kg2 << 4) | g) << 3) + (half << 2)) = o;
    }
    __syncthreads();

    // ---- phase B: MFMA (wave wv -> columns [wv*16, wv*16+16)) ----
    int r16 = lane & 15, kg = lane >> 4;
    short8 bb0 = *(const short8*)(bfrag + lane * 8);         // ks=0, conflict-free
    short8 bb1 = *(const short8*)(bfrag + 512 + lane * 8);   // ks=1

    f32x4 z = {0.f, 0.f, 0.f, 0.f};
    f32x4 acc2 = __builtin_amdgcn_mfma_f32_16x16x32_bf16(aflo, bb0, z, 0, 0, 0);
    acc2 = __builtin_amdgcn_mfma_f32_16x16x32_bf16(afhi, bb1, acc2, 0, 0, 0);

    int row = blockIdx.x * 16 + r16;
    if (row < n) {
        float di = dinv[row];
        ushort4 o;
        o.x = f2bf(acc2[0] * di); o.y = f2bf(acc2[1] * di);
        o.z = f2bf(acc2[2] * di); o.w = f2bf(acc2[3] * di);
        *(ushort4*)((char*)out + (((unsigned)row << 7) + ((unsigned)wv << 5) + ((unsigned)kg << 3))) = o;
    }
}

// =================== pull2 + fused decode: out[d] = relu(dinv*(...)+b2) . Wd + bd ===================
__global__ __launch_bounds__(256) void k_pull2(
    const ushort_t* __restrict__ hs, const float* __restrict__ dinv,
    const int* __restrict__ row_ptr, const int* __restrict__ cnt,
    const int* __restrict__ col, const float* __restrict__ bias,
    const float* __restrict__ Wd, const float* __restrict__ bd,
    float* __restrict__ outv, int n)
{
    int d = blockIdx.x * 16 + (threadIdx.x >> 4);
    if (d >= n) return;
    int lt = threadIdx.x & 15;            // lane in group
    int fo = lt << 2;                     // feature offset (4 features/lane)
    int grpbase = threadIdx.x & 48;       // group base lane within wave
    const char* __restrict__ hp = (const char*)hs;
    unsigned lt8 = (unsigned)lt << 3;
    int beg = row_ptr[d], deg = cnt[d];

    // self-loop (bf16 row, 8B/lane)
    uint2 sv = *(const uint2*)(hp + (((unsigned)d << 7) + lt8));
    float4 acc = make_float4(bflo(sv.x), bfhi(sv.x), bflo(sv.y), bfhi(sv.y));

    for (int jb = 0; jb < deg; jb += 16) {
        int m = deg - jb; if (m > 16) m = 16;
        int idx = (lt < m) ? col[beg + jb + lt] : 0;
        uint2 v[16];
#pragma unroll
        for (int u = 0; u < 16; ++u) {
            int kk = (u < m) ? u : (m - 1);                  // clamp: dup loads hit L1
            int s = __shfl(idx, grpbase + kk, 64);
            v[u] = *(const uint2*)(hp + (((unsigned)s << 7) + lt8));
        }
#pragma unroll
        for (int u = 0; u < 16; ++u) {
            if (u < m) {
                acc.x += bflo(v[u].x); acc.y += bfhi(v[u].x);
                acc.z += bflo(v[u].y); acc.w += bfhi(v[u].y);
            }
        }
    }

    float di = dinv[d];
    float4 bv = *(const float4*)(bias + fo);
    float rx = fmaxf(fmaf(acc.x, di, bv.x), 0.0f);
    float ry = fmaxf(fmaf(acc.y, di, bv.y), 0.0f);
    float rz = fmaxf(fmaf(acc.z, di, bv.z), 0.0f);
    float rw = fmaxf(fmaf(acc.w, di, bv.w), 0.0f);

    float4 wv = *(const float4*)(Wd + fo);
    float vsum = rx * wv.x + ry * wv.y + rz * wv.z + rw * wv.w;
#pragma unroll
    for (int o = 1; o < 16; o <<= 1) vsum += __shfl_xor(vsum, o, 64);
    if (lt == 0) outv[d] = vsum + bd[0];
}

extern "C" void kernel_launch(void* const* d_in, const int* in_sizes, int n_in,
                              void* d_out, int out_size, void* d_ws, size_t ws_size,
                              hipStream_t stream) {
    const float* x  = (const float*)d_in[0];
    const int*   ei = (const int*)d_in[1];
    const float* W1 = (const float*)d_in[2];
    const float* b1 = (const float*)d_in[3];
    const float* W2 = (const float*)d_in[4];
    const float* b2 = (const float*)d_in[5];
    const float* Wd = (const float*)d_in[6];
    const float* bd = (const float*)d_in[7];
    float* out = (float*)d_out;

    int n = in_sizes[0] / 128;
    int E = in_sizes[1] / 2;
    const int* src = ei;
    const int* dst = ei + E;

    int NB = (n + (1 << SH) - 1) >> SH;     // dst buckets of 256 nodes (~391)
    int chunk = (E + NBLK - 1) / NBLK;
    int ntot = NB * NBLK;                   // hist matrix size (~100k)
    int nsb = (ntot + 1023) / 1024;         // scan blocks over hmat (<= 2048)
    int ntiles = (n + 15) / 16;             // 16-row MFMA tiles

    // workspace layout (4-byte elems) — pairs aliases bufH region (build ends before gemm1)
    float* dinv    = (float*)d_ws;                    // n
    float* bufH    = dinv + n;                        // 64n f32 region; holds bf16 hs
    float* bufA    = bufH + (size_t)n * NF;           // 64n f32 region (hs2)
    int*   counts  = (int*)(bufA + (size_t)n * NF);   // n
    int*   row_ptr = counts + n;                      // n
    int*   col     = row_ptr + n;                     // E
    int*   hmat    = col + E;                         // NB*NBLK
    int*   bptr    = hmat + ntot;                     // NB+1
    int*   bsums   = bptr + NB + 1;                   // <=2048
    int*   wfrags  = bsums + 2048;                    // 6144 ints: w1f (4096) + w2f (2048)
    ushort_t* w1f  = (ushort_t*)wfrags;               // 8192 bf16 pre-swizzled W1 frags
    ushort_t* w2f  = w1f + 8192;                      // 4096 bf16 pre-swizzled W2 frags
    int*   pairs   = (int*)bufH;                      // E (build lifetime only)
    ushort_t* hsb  = (ushort_t*)bufH;                 // 64n bf16 layer-1 hs
    ushort_t* hs2b = (ushort_t*)bufA;                 // 64n bf16 layer-2 hs

    // ---- bucket sort by dst (contention-free) + W frag pre-swizzle ----
    k_histA<<<NBLK, 256, 0, stream>>>(dst, hmat, E, NB, chunk, W1, W2, w1f, w2f);
    k_scan_a<<<nsb, 256, 0, stream>>>(hmat, hmat, bsums, ntot);
    k_scan_addb<<<(ntot + 255) / 256, 256, 0, stream>>>(hmat, bsums, bptr, ntot, E);
    k_placeB<<<NBLK, 256, 0, stream>>>(src, dst, hmat, pairs, E, NB, chunk);

    // ---- fused node-level CSR + dinv (one block per 256-node bucket) ----
    k_csr<<<NB, 256, 0, stream>>>(bptr, pairs, row_ptr, counts, dinv, col, n);

    // ---- layer 1 (MFMA): hs = bf16((x @ W1) * dinv) ----
    k_mm1<<<(ntiles + 3) / 4, 256, 0, stream>>>(x, w1f, dinv, hsb, n);

    // ---- fused pull1 (+b1, relu) + GEMM2 (MFMA): hs2 = bf16((act @ W2) * dinv) ----
    k_pullmm<<<(n + 15) / 16, 256, 0, stream>>>(hsb, dinv, row_ptr, counts, col, b1,
                                                w2f, hs2b, n);

    // ---- pull2 (+b2, relu) + fused decode ----
    k_pull2<<<(n + 15) / 16, 256, 0, stream>>>(hs2b, dinv, row_ptr, counts, col, b2,
                                               Wd, bd, out, n);
}

// Round 24
// 124.284 us; speedup vs baseline: 2.2728x; 1.0183x over previous
//
#include <hip/hip_runtime.h>

#define NF 64      // hidden width (both layers)
#define NBLK 256   // chunks for the two-pass bucket sort
#define SH 8       // bucket = dst >> SH  (256 nodes per bucket)
#define BMSK 255
#define MAXNB 2048 // LDS histogram capacity (NB = ceil(n/256) <= 2048 -> n <= 524288)

typedef unsigned short ushort_t;
typedef __attribute__((ext_vector_type(8))) short short8;   // 8 bf16 = 4 VGPR (MFMA A/B frag)
typedef __attribute__((ext_vector_type(4))) float f32x4;    // MFMA C/D frag

__device__ inline ushort_t f2bf(float f) {               // RNE f32 -> bf16
    unsigned u = __float_as_uint(f);
    return (ushort_t)((u + 0x7fffu + ((u >> 16) & 1u)) >> 16);
}
__device__ inline float bfhi(unsigned x) { return __uint_as_float(x & 0xffff0000u); }
__device__ inline float bflo(unsigned x) { return __uint_as_float(x << 16); }

#define PACK8(b, ua, ub) \
    b[0] = (short)f2bf(ua.x); b[1] = (short)f2bf(ua.y); \
    b[2] = (short)f2bf(ua.z); b[3] = (short)f2bf(ua.w); \
    b[4] = (short)f2bf(ub.x); b[5] = (short)f2bf(ub.y); \
    b[6] = (short)f2bf(ub.z); b[7] = (short)f2bf(ub.w);

// =================== scan utilities ===================

__device__ inline int wave_incl_scan(int x, int lane) {
#pragma unroll
    for (int o = 1; o < 64; o <<= 1) { int y = __shfl_up(x, o, 64); if (lane >= o) x += y; }
    return x;
}

// 1024 elements per block (256 threads x 4); in-place safe
__global__ __launch_bounds__(256) void k_scan_a(const int* __restrict__ in, int* __restrict__ out,
                                                int* __restrict__ bsums, int n) {
    int t = threadIdx.x, lane = t & 63, wv = t >> 6;
    int base = blockIdx.x * 1024 + t * 4;
    int v[4]; int s = 0;
#pragma unroll
    for (int k = 0; k < 4; ++k) { int i = base + k; int x = (i < n) ? in[i] : 0; v[k] = s; s += x; }
    int incl = wave_incl_scan(s, lane);
    __shared__ int ws[4];
    if (lane == 63) ws[wv] = incl;
    __syncthreads();
    int wofs = 0;
#pragma unroll
    for (int w = 0; w < 4; ++w) if (w < wv) wofs += ws[w];
    int texcl = wofs + incl - s;
#pragma unroll
    for (int k = 0; k < 4; ++k) { int i = base + k; if (i < n) out[i] = texcl + v[k]; }
    if (t == 255) bsums[blockIdx.x] = wofs + incl;
}

// add block sums (prefix computed locally from raw bsums: <=2048 entries, one wave);
// also emit bucket pointers (bptr[b] = scanned hmat[b*NBLK], bptr[NB] = E)
__global__ __launch_bounds__(256) void k_scan_addb(int* __restrict__ data, const int* __restrict__ bsums,
                                                   int* __restrict__ bptr, int ntot, int E) {
    __shared__ int off_s;
    int t = threadIdx.x;
    int myChunk = (int)(blockIdx.x >> 2);          // this block's 1024-chunk index
    if (t < 64) {
        int s = 0;
        for (int i = t; i < myChunk; i += 64) s += bsums[i];
#pragma unroll
        for (int o = 32; o > 0; o >>= 1) s += __shfl_xor(s, o, 64);
        if (t == 0) off_s = s;
    }
    __syncthreads();
    int off = off_s;
    int i = blockIdx.x * 256 + t;
    if (i < ntot) {
        int v = data[i] + off;
        data[i] = v;
        if ((i & (NBLK - 1)) == 0) bptr[i / NBLK] = v;
    }
    if (i == 0) bptr[ntot / NBLK] = E;
}

// =================== contention-free bucket sort (bucket = dst >> SH, 256 nodes/bucket) ===================
// prologue: pre-swizzle W1/W2 into bf16 MFMA-fragment order in global ws (once, not per GEMM block)

__global__ __launch_bounds__(256) void k_histA(const int* __restrict__ dst, int* __restrict__ hmat,
                                               int E, int NB, int chunk,
                                               const float* __restrict__ W1, const float* __restrict__ W2,
                                               ushort_t* __restrict__ w1f, ushort_t* __restrict__ w2f) {
    __shared__ int h[MAXNB];
    int blk = blockIdx.x;
    // ---- W pre-swizzle (12288 elems over 65536 threads) ----
    int gid = blk * 256 + threadIdx.x;
    if (gid < 8192) {                                     // W1: [128][64]
        int k = gid >> 6, c = gid & 63;
        int f = ((k >> 5) << 2) | (c >> 4);
        int ln = (c & 15) | (((k >> 3) & 3) << 4);
        w1f[f * 512 + ln * 8 + (k & 7)] = f2bf(W1[gid]);
    } else if (gid < 12288) {                             // W2: [64][64]
        int i2 = gid - 8192;
        int k = i2 >> 6, c = i2 & 63;
        int f = ((k >> 5) << 2) | (c >> 4);
        int ln = (c & 15) | (((k >> 3) & 3) << 4);
        w2f[f * 512 + ln * 8 + (k & 7)] = f2bf(W2[i2]);
    }

    for (int i = threadIdx.x; i < NB; i += 256) h[i] = 0;
    __syncthreads();
    int beg = blk * chunk, end = beg + chunk; if (end > E) end = E;
    for (int e = beg + threadIdx.x; e < end; e += 256) atomicAdd(&h[dst[e] >> SH], 1);
    __syncthreads();
    for (int i = threadIdx.x; i < NB; i += 256) hmat[i * NBLK + blk] = h[i];
}

__global__ __launch_bounds__(256) void k_placeB(const int* __restrict__ src, const int* __restrict__ dst,
                                                const int* __restrict__ hmat, int* __restrict__ pairs,
                                                int E, int NB, int chunk) {
    __shared__ int cur[MAXNB];
    int blk = blockIdx.x;
    for (int i = threadIdx.x; i < NB; i += 256) cur[i] = hmat[i * NBLK + blk];
    __syncthreads();
    int beg = blk * chunk, end = beg + chunk; if (end > E) end = E;
    for (int e = beg + threadIdx.x; e < end; e += 256) {
        int s = src[e], d = dst[e];
        int off = atomicAdd(&cur[d >> SH], 1);
        pairs[off] = (s << SH) | (d & BMSK);
    }
}

// =================== fused CSR + GEMM1 ===================
// One block per 256-node bucket:
//   phase 1: node hist + 256-scan -> row_ptr/cnt/dinv (dinv cached in LDS ds[])
//   phase 2: col placement via LDS cursors
//   phase 3: mm1 for this bucket's 16 MFMA tiles (wave wv -> tiles wv*4..wv*4+3):
//            hs[row] = bf16((x[row] @ W1) * dinv[row]), A-frags from pre-swizzled w1f.
__global__ __launch_bounds__(256) void k_csrmm(
    const int* __restrict__ bptr, const int* __restrict__ pairs,
    int* __restrict__ row_ptr, int* __restrict__ cnt,
    float* __restrict__ dinv, int* __restrict__ col,
    const float* __restrict__ X, const ushort_t* __restrict__ w1f,
    ushort_t* __restrict__ hsb, int n)
{
    __shared__ int h[256];
    __shared__ int cur[256];
    __shared__ float ds[256];
    __shared__ int ws[4];
    int b = blockIdx.x, t = threadIdx.x;
    h[t] = 0;
    __syncthreads();
    int beg = bptr[b], end = bptr[b + 1];
    for (int j = beg + t; j < end; j += 256) atomicAdd(&h[pairs[j] & BMSK], 1);
    __syncthreads();
    int c = h[t];
    int incl = wave_incl_scan(c, t & 63);
    if ((t & 63) == 63) ws[t >> 6] = incl;
    __syncthreads();
    int wofs = 0;
#pragma unroll
    for (int w = 0; w < 4; ++w) if (w < (t >> 6)) wofs += ws[w];
    int ex = wofs + incl - c;
    int node0 = b << SH;
    int node = node0 + t;
    float di_t = rsqrtf(1.0f + (float)c);
    if (node < n) {
        row_ptr[node] = beg + ex;
        cnt[node] = c;
        dinv[node] = di_t;
    }
    cur[t] = beg + ex;
    ds[t] = di_t;
    __syncthreads();

    // phase 2: place col
    for (int j = beg + t; j < end; j += 256) {
        int pk = pairs[j];
        int p = atomicAdd(&cur[pk & BMSK], 1);
        col[p] = pk >> SH;
    }

    // phase 3: mm1 for bucket rows (no sync needed: uses only ds[] + globals)
    int lane = t & 63, wv = t >> 6;
    int r16 = lane & 15, kg = lane >> 4;

    short8 a0[4], a1[4], a2[4], a3[4];
#pragma unroll
    for (int f = 0; f < 4; ++f) {
        a0[f] = *(const short8*)(w1f + (0 + f) * 512 + lane * 8);
        a1[f] = *(const short8*)(w1f + (4 + f) * 512 + lane * 8);
        a2[f] = *(const short8*)(w1f + (8 + f) * 512 + lane * 8);
        a3[f] = *(const short8*)(w1f + (12 + f) * 512 + lane * 8);
    }

    for (int tile = wv; tile < 16; tile += 4) {
        int lrow = tile * 16 + r16;                  // local row in bucket
        int row = node0 + lrow;
        int r = (row < n) ? row : (n - 1);           // clamp: dup loads, stores guarded
        const float* pX = X + (size_t)r * 128 + kg * 8;

        float4 u0a = *(const float4*)(pX + 0),   u0b = *(const float4*)(pX + 4);
        float4 u1a = *(const float4*)(pX + 32),  u1b = *(const float4*)(pX + 36);
        float4 u2a = *(const float4*)(pX + 64),  u2b = *(const float4*)(pX + 68);
        float4 u3a = *(const float4*)(pX + 96),  u3b = *(const float4*)(pX + 100);

        short8 b0, b1, b2, b3;
        PACK8(b0, u0a, u0b); PACK8(b1, u1a, u1b);
        PACK8(b2, u2a, u2b); PACK8(b3, u3a, u3b);

        f32x4 z = {0.f, 0.f, 0.f, 0.f};
        f32x4 acc[4];
#pragma unroll
        for (int f = 0; f < 4; ++f)
            acc[f] = __builtin_amdgcn_mfma_f32_16x16x32_bf16(a0[f], b0, z, 0, 0, 0);
#pragma unroll
        for (int f = 0; f < 4; ++f)
            acc[f] = __builtin_amdgcn_mfma_f32_16x16x32_bf16(a1[f], b1, acc[f], 0, 0, 0);
#pragma unroll
        for (int f = 0; f < 4; ++f)
            acc[f] = __builtin_amdgcn_mfma_f32_16x16x32_bf16(a2[f], b2, acc[f], 0, 0, 0);
#pragma unroll
        for (int f = 0; f < 4; ++f)
            acc[f] = __builtin_amdgcn_mfma_f32_16x16x32_bf16(a3[f], b3, acc[f], 0, 0, 0);

        if (row < n) {
            float di = ds[lrow];
#pragma unroll
            for (int f = 0; f < 4; ++f) {
                ushort4 o;
                o.x = f2bf(acc[f][0] * di); o.y = f2bf(acc[f][1] * di);
                o.z = f2bf(acc[f][2] * di); o.w = f2bf(acc[f][3] * di);
                *(ushort4*)(hsb + (size_t)row * NF + f * 16 + kg * 4) = o;
            }
        }
    }
}

// =================== fused pull1 + GEMM2 ===================
// Block = 256 threads = 16 dst nodes = one 16-row MFMA tile.
// Phase A (pull): act_row(d) = relu(dinv[d]*(hs[d]+sum hs[src])+b1), written in B-frag order
//   to LDS bfrag (2 KB). Phase B: A-frags from pre-swizzled global w2f (prefetched before
//   the gather loop); wave wv computes column slab [wv*16, wv*16+16).
__global__ __launch_bounds__(256) void k_pullmm(
    const ushort_t* __restrict__ hs, const float* __restrict__ dinv,
    const int* __restrict__ row_ptr, const int* __restrict__ cnt,
    const int* __restrict__ col, const float* __restrict__ bias,
    const ushort_t* __restrict__ w2f, ushort_t* __restrict__ out, int n)
{
    __shared__ ushort_t bfrag[1024];             // act tile in B-frag order (2 KB)
    int t = threadIdx.x;
    int lane = t & 63, wv = t >> 6;

    // prefetch A-frags (L2-resident; latency hides under the gather loop)
    short8 aflo = *(const short8*)(w2f + wv * 512 + lane * 8);
    short8 afhi = *(const short8*)(w2f + (4 + wv) * 512 + lane * 8);

    // ---- phase A: pull (one 16-lane group per node) ----
    int d = blockIdx.x * 16 + (t >> 4);
    int lt = t & 15;
    int fo = lt << 2;
    int grpbase = t & 48;
    const char* __restrict__ hp = (const char*)hs;
    unsigned lt8 = (unsigned)lt << 3;
    float rx = 0.f, ry = 0.f, rz = 0.f, rw = 0.f;
    if (d < n) {
        uint2 sv = *(const uint2*)(hp + (((unsigned)d << 7) + lt8));
        float4 acc = make_float4(bflo(sv.x), bfhi(sv.x), bflo(sv.y), bfhi(sv.y));
        int beg = row_ptr[d], deg = cnt[d];
        for (int jb = 0; jb < deg; jb += 16) {
            int m = deg - jb; if (m > 16) m = 16;
            int idx = (lt < m) ? col[beg + jb + lt] : 0;
            uint2 v[16];
#pragma unroll
            for (int u = 0; u < 16; ++u) {
                int kk = (u < m) ? u : (m - 1);              // clamp: dup loads hit L1
                int s = __shfl(idx, grpbase + kk, 64);
                v[u] = *(const uint2*)(hp + (((unsigned)s << 7) + lt8));
            }
#pragma unroll
            for (int u = 0; u < 16; ++u) {
                if (u < m) {
                    acc.x += bflo(v[u].x); acc.y += bfhi(v[u].x);
                    acc.z += bflo(v[u].y); acc.w += bfhi(v[u].y);
                }
            }
        }
        float di = dinv[d];
        float4 bv = *(const float4*)(bias + fo);
        rx = fmaxf(fmaf(acc.x, di, bv.x), 0.0f);
        ry = fmaxf(fmaf(acc.y, di, bv.y), 0.0f);
        rz = fmaxf(fmaf(acc.z, di, bv.z), 0.0f);
        rw = fmaxf(fmaf(acc.w, di, bv.w), 0.0f);
    }
    {
        ushort4 o;
        o.x = f2bf(rx); o.y = f2bf(ry); o.z = f2bf(rz); o.w = f2bf(rw);
        int g = t >> 4;
        int ks = lt >> 3, kg2 = (lt >> 1) & 3, half = lt & 1;
        *(ushort4*)(bfrag + ks * 512 + (((kg2 << 4) | g) << 3) + (half << 2)) = o;
    }
    __syncthreads();

    // ---- phase B: MFMA (wave wv -> columns [wv*16, wv*16+16)) ----
    int r16 = lane & 15, kg = lane >> 4;
    short8 bb0 = *(const short8*)(bfrag + lane * 8);         // ks=0, conflict-free
    short8 bb1 = *(const short8*)(bfrag + 512 + lane * 8);   // ks=1

    f32x4 z = {0.f, 0.f, 0.f, 0.f};
    f32x4 acc2 = __builtin_amdgcn_mfma_f32_16x16x32_bf16(aflo, bb0, z, 0, 0, 0);
    acc2 = __builtin_amdgcn_mfma_f32_16x16x32_bf16(afhi, bb1, acc2, 0, 0, 0);

    int row = blockIdx.x * 16 + r16;
    if (row < n) {
        float di = dinv[row];
        ushort4 o;
        o.x = f2bf(acc2[0] * di); o.y = f2bf(acc2[1] * di);
        o.z = f2bf(acc2[2] * di); o.w = f2bf(acc2[3] * di);
        *(ushort4*)((char*)out + (((unsigned)row << 7) + ((unsigned)wv << 5) + ((unsigned)kg << 3))) = o;
    }
}

// =================== pull2 + fused decode: out[d] = relu(dinv*(...)+b2) . Wd + bd ===================
__global__ __launch_bounds__(256) void k_pull2(
    const ushort_t* __restrict__ hs, const float* __restrict__ dinv,
    const int* __restrict__ row_ptr, const int* __restrict__ cnt,
    const int* __restrict__ col, const float* __restrict__ bias,
    const float* __restrict__ Wd, const float* __restrict__ bd,
    float* __restrict__ outv, int n)
{
    int d = blockIdx.x * 16 + (threadIdx.x >> 4);
    if (d >= n) return;
    int lt = threadIdx.x & 15;            // lane in group
    int fo = lt << 2;                     // feature offset (4 features/lane)
    int grpbase = threadIdx.x & 48;       // group base lane within wave
    const char* __restrict__ hp = (const char*)hs;
    unsigned lt8 = (unsigned)lt << 3;
    int beg = row_ptr[d], deg = cnt[d];

    // self-loop (bf16 row, 8B/lane)
    uint2 sv = *(const uint2*)(hp + (((unsigned)d << 7) + lt8));
    float4 acc = make_float4(bflo(sv.x), bfhi(sv.x), bflo(sv.y), bfhi(sv.y));

    for (int jb = 0; jb < deg; jb += 16) {
        int m = deg - jb; if (m > 16) m = 16;
        int idx = (lt < m) ? col[beg + jb + lt] : 0;
        uint2 v[16];
#pragma unroll
        for (int u = 0; u < 16; ++u) {
            int kk = (u < m) ? u : (m - 1);                  // clamp: dup loads hit L1
            int s = __shfl(idx, grpbase + kk, 64);
            v[u] = *(const uint2*)(hp + (((unsigned)s << 7) + lt8));
        }
#pragma unroll
        for (int u = 0; u < 16; ++u) {
            if (u < m) {
                acc.x += bflo(v[u].x); acc.y += bfhi(v[u].x);
                acc.z += bflo(v[u].y); acc.w += bfhi(v[u].y);
            }
        }
    }

    float di = dinv[d];
    float4 bv = *(const float4*)(bias + fo);
    float rx = fmaxf(fmaf(acc.x, di, bv.x), 0.0f);
    float ry = fmaxf(fmaf(acc.y, di, bv.y), 0.0f);
    float rz = fmaxf(fmaf(acc.z, di, bv.z), 0.0f);
    float rw = fmaxf(fmaf(acc.w, di, bv.w), 0.0f);

    float4 wv = *(const float4*)(Wd + fo);
    float vsum = rx * wv.x + ry * wv.y + rz * wv.z + rw * wv.w;
#pragma unroll
    for (int o = 1; o < 16; o <<= 1) vsum += __shfl_xor(vsum, o, 64);
    if (lt == 0) outv[d] = vsum + bd[0];
}

extern "C" void kernel_launch(void* const* d_in, const int* in_sizes, int n_in,
                              void* d_out, int out_size, void* d_ws, size_t ws_size,
                              hipStream_t stream) {
    const float* x  = (const float*)d_in[0];
    const int*   ei = (const int*)d_in[1];
    const float* W1 = (const float*)d_in[2];
    const float* b1 = (const float*)d_in[3];
    const float* W2 = (const float*)d_in[4];
    const float* b2 = (const float*)d_in[5];
    const float* Wd = (const float*)d_in[6];
    const float* bd = (const float*)d_in[7];
    float* out = (float*)d_out;

    int n = in_sizes[0] / 128;
    int E = in_sizes[1] / 2;
    const int* src = ei;
    const int* dst = ei + E;

    int NB = (n + (1 << SH) - 1) >> SH;     // dst buckets of 256 nodes (~391)
    int chunk = (E + NBLK - 1) / NBLK;
    int ntot = NB * NBLK;                   // hist matrix size (~100k)
    int nsb = (ntot + 1023) / 1024;         // scan blocks over hmat (<= 2048)

    // workspace layout (4-byte elems)
    // bufH: hsb (bf16, 12.8MB of the 25.6MB region). bufA: hs2b (lower half) + pairs (upper half).
    // pairs is read by k_csrmm while it writes hsb -> MUST NOT alias bufH anymore.
    float* dinv    = (float*)d_ws;                    // n
    float* bufH    = dinv + n;                        // 64n f32 region
    float* bufA    = bufH + (size_t)n * NF;           // 64n f32 region
    int*   counts  = (int*)(bufA + (size_t)n * NF);   // n
    int*   row_ptr = counts + n;                      // n
    int*   col     = row_ptr + n;                     // E
    int*   hmat    = col + E;                         // NB*NBLK
    int*   bptr    = hmat + ntot;                     // NB+1
    int*   bsums   = bptr + NB + 1;                   // <=2048
    int*   wfrags  = bsums + 2048;                    // 6144 ints: w1f (4096) + w2f (2048)
    ushort_t* w1f  = (ushort_t*)wfrags;               // 8192 bf16 pre-swizzled W1 frags
    ushort_t* w2f  = w1f + 8192;                      // 4096 bf16 pre-swizzled W2 frags
    ushort_t* hsb  = (ushort_t*)bufH;                 // 64n bf16 layer-1 hs
    ushort_t* hs2b = (ushort_t*)bufA;                 // 64n bf16 layer-2 hs (lower 32n f32)
    int*   pairs   = (int*)(bufA + (size_t)n * 32);   // E ints in upper half of bufA region

    // ---- bucket sort by dst (contention-free) + W frag pre-swizzle ----
    k_histA<<<NBLK, 256, 0, stream>>>(dst, hmat, E, NB, chunk, W1, W2, w1f, w2f);
    k_scan_a<<<nsb, 256, 0, stream>>>(hmat, hmat, bsums, ntot);
    k_scan_addb<<<(ntot + 255) / 256, 256, 0, stream>>>(hmat, bsums, bptr, ntot, E);
    k_placeB<<<NBLK, 256, 0, stream>>>(src, dst, hmat, pairs, E, NB, chunk);

    // ---- fused node CSR + dinv + GEMM1 (MFMA): hs = bf16((x @ W1) * dinv) ----
    k_csrmm<<<NB, 256, 0, stream>>>(bptr, pairs, row_ptr, counts, dinv, col,
                                    x, w1f, hsb, n);

    // ---- fused pull1 (+b1, relu) + GEMM2 (MFMA): hs2 = bf16((act @ W2) * dinv) ----
    k_pullmm<<<(n + 15) / 16, 256, 0, stream>>>(hsb, dinv, row_ptr, counts, col, b1,
                                                w2f, hs2b, n);

    // ---- pull2 (+b2, relu) + fused decode ----
    k_pull2<<<(n + 15) / 16, 256, 0, stream>>>(hs2b, dinv, row_ptr, counts, col, b2,
                                               Wd, bd, out, n);
}